// Round 11
// baseline (6734.087 us; speedup 1.0000x reference)
//
#include <hip/hip_runtime.h>
#include <math.h>

#define TT 32
#define DD 64
#define NN 1024
#define VV 64
#define RR 4
#define HH 512

typedef unsigned int uint_t;
typedef unsigned short ushort_t;

__device__ __forceinline__ float sigf(float x) { return 1.0f / (1.0f + __expf(-x)); }
__device__ __forceinline__ float splus(float x) {
  return (x > 0.f) ? (x + log1pf(__expf(-x))) : log1pf(__expf(x));
}
__device__ __forceinline__ ushort_t bfr(float f) {
  uint_t u = __float_as_uint(f);
  return (ushort_t)((u + 0x7fffu + ((u >> 16) & 1u)) >> 16);
}
__device__ __forceinline__ float bflo(uint_t u) { return __uint_as_float(u << 16); }
__device__ __forceinline__ float bfhi(uint_t u) { return __uint_as_float(u & 0xffff0000u); }
__device__ __forceinline__ uint_t packbf(float a, float b) {
  return (uint_t)bfr(a) | ((uint_t)bfr(b) << 16);
}
// 8 bf16 weights (uint4) dot 8 fp32 activations
__device__ __forceinline__ float dot8bf(uint4 w, float4 ha, float4 hb) {
  float s;
  s  = bflo(w.x) * ha.x + bfhi(w.x) * ha.y;
  s += bflo(w.y) * ha.z + bfhi(w.y) * ha.w;
  s += bflo(w.z) * hb.x + bfhi(w.z) * hb.y;
  s += bflo(w.w) * hb.z + bfhi(w.w) * hb.w;
  return s;
}

// ============ pre-kernels (every launch; deterministic) ============
__global__ void build_gw(const float* __restrict__ W_ih, const float* __restrict__ W_hh,
                         const float* __restrict__ out_W, uint_t* __restrict__ W2g) {
  int idx = blockIdx.x * 256 + threadIdx.x;           // 2112*416
  if (idx >= 2112 * 416) return;
  int r = idx / 416, kp = idx - r * 416;
  float v[2];
  #pragma unroll
  for (int q = 0; q < 2; ++q) {
    int k = 2 * kp + q;
    float f;
    if (r < 2048) {
      int h = r >> 2, g = r & 3, row = g * 512 + h;
      f = (k < 320) ? W_ih[(size_t)row * 320 + k] : W_hh[(size_t)row * 512 + (k - 320)];
    } else {
      int j = r - 2048;
      if (k < 64) f = 0.f;
      else if (k < 320) f = out_W[(size_t)j * 768 + 512 + (k - 64)];
      else f = out_W[(size_t)j * 768 + (k - 320)];
    }
    v[q] = f;
  }
  W2g[idx] = packbf(v[0], v[1]);
}
__global__ void build_hw(const float* __restrict__ read_W, const float* __restrict__ write_W,
                         uint_t* __restrict__ W2h) {
  int idx = blockIdx.x * 256 + threadIdx.x;           // 1072*256
  if (idx >= 1072 * 256) return;
  int r = idx >> 8, kp = idx & 255;
  const float* src = (r < 280) ? (read_W + (size_t)r * 512) : (write_W + (size_t)(r - 280) * 512);
  W2h[idx] = packbf(src[2 * kp], src[2 * kp + 1]);
}
__global__ void bias_kernel(const float* __restrict__ bi, const float* __restrict__ bh,
                            float* __restrict__ o) {
  int i = blockIdx.x * 256 + threadIdx.x;
  if (i < 2048) o[i] = bi[i] + bh[i];
}
__global__ void k0_init(const float* __restrict__ x, const float* __restrict__ mem_bias,
                        const float* __restrict__ h_bias, const float* __restrict__ c_bias,
                        const float* __restrict__ read_init,
                        ushort_t* __restrict__ g_mem, uint_t* __restrict__ A2,
                        float* __restrict__ g_c, float* __restrict__ g_ws) {
  const int b = blockIdx.x, tid = threadIdx.x;
  {
    const float4* src = (const float4*)(mem_bias + (size_t)tid * VV);
    uint4* dst = (uint4*)(g_mem + (size_t)b * (NN * VV) + (size_t)tid * VV);
    #pragma unroll
    for (int p = 0; p < 8; ++p) {
      float4 va = src[2 * p], vb = src[2 * p + 1];
      uint4 o;
      o.x = packbf(va.x, va.y); o.y = packbf(va.z, va.w);
      o.z = packbf(vb.x, vb.y); o.w = packbf(vb.z, vb.w);
      dst[p] = o;
    }
  }
  if (tid < 416) {
    float v0, v1;
    if (tid < 32)      { v0 = x[((size_t)b * TT) * DD + 2 * tid]; v1 = x[((size_t)b * TT) * DD + 2 * tid + 1]; }
    else if (tid < 160){ int e = 2 * (tid - 32); v0 = read_init[e]; v1 = read_init[e + 1]; }
    else               { int e = 2 * (tid - 160); v0 = h_bias[e]; v1 = h_bias[e + 1]; }
    A2[(size_t)tid * 64 + b] = packbf(v0, v1);
  }
  if (tid < 512) g_c[(size_t)tid * 64 + b] = c_bias[tid];
  for (int i = tid; i < 8192; i += 1024) g_ws[(size_t)b * 8192 + i] = 0.f;
}

// ============ K1: gates GEMM + LSTM + out(t-1) rows ============
__global__ __launch_bounds__(512) void k1_gates(
    int t, int nGate, int par,
    const uint_t* __restrict__ W2g, const float* __restrict__ gbias,
    uint_t* __restrict__ A2, float* __restrict__ g_c,
    const float* __restrict__ out_b, float* __restrict__ out,
    float* __restrict__ h_tr) {
  const int blk = blockIdx.x, tid = threadIdx.x;
  const int lane = tid & 63, u = tid >> 6;
  const bool isGate = (blk < nGate);
  if (!isGate && t == 0) return;
  __shared__ uint_t s_tile[52 * 64];
  __shared__ float s_h[8 * 64];
  float acc0 = 0.f, acc1 = 0.f, acc2 = 0.f, acc3 = 0.f;
  const int hglob = blk * 8 + u;
  const int orow = 2048 + (blk - nGate) * 8 + u;
  const size_t wbase = isGate ? (size_t)(hglob * 4) * 416 : (size_t)orow * 416;

  for (int c = 0; c < 8; ++c) {
    for (int i = tid; i < 52 * 64; i += 512) {
      int kk = i >> 6, bb = i & 63;
      int kpg = c * 52 + kk;
      int phys = (kpg < 160) ? kpg : kpg + 256 * par;
      s_tile[i] = A2[(size_t)phys * 64 + bb];
    }
    __syncthreads();
    const uint4* w4 = (const uint4*)(W2g + wbase) + c * 13;
    if (isGate) {
      #pragma unroll
      for (int q = 0; q < 13; ++q) {
        uint4 wA = w4[q], wB = w4[104 + q], wC = w4[208 + q], wD = w4[312 + q];
        const uint_t* pA = (const uint_t*)&wA;
        const uint_t* pB = (const uint_t*)&wB;
        const uint_t* pC = (const uint_t*)&wC;
        const uint_t* pD = (const uint_t*)&wD;
        #pragma unroll
        for (int jj = 0; jj < 4; ++jj) {
          uint_t ua = s_tile[(q * 4 + jj) * 64 + lane];
          float a0 = bflo(ua), a1 = bfhi(ua);
          acc0 += bflo(pA[jj]) * a0 + bfhi(pA[jj]) * a1;
          acc1 += bflo(pB[jj]) * a0 + bfhi(pB[jj]) * a1;
          acc2 += bflo(pC[jj]) * a0 + bfhi(pC[jj]) * a1;
          acc3 += bflo(pD[jj]) * a0 + bfhi(pD[jj]) * a1;
        }
      }
    } else {
      #pragma unroll
      for (int q = 0; q < 13; ++q) {
        uint4 wA = w4[q];
        const uint_t* pA = (const uint_t*)&wA;
        #pragma unroll
        for (int jj = 0; jj < 4; ++jj) {
          uint_t ua = s_tile[(q * 4 + jj) * 64 + lane];
          acc0 += bflo(pA[jj]) * bflo(ua) + bfhi(pA[jj]) * bfhi(ua);
        }
      }
    }
    __syncthreads();
  }

  if (isGate) {
    float gi = acc0 + gbias[hglob];
    float gf = acc1 + gbias[512 + hglob];
    float gg = acc2 + gbias[1024 + hglob];
    float go = acc3 + gbias[1536 + hglob];
    float c0 = g_c[(size_t)hglob * 64 + lane];
    float cn = sigf(gf) * c0 + sigf(gi) * tanhf(gg);
    float hn = sigf(go) * tanhf(cn);
    g_c[(size_t)hglob * 64 + lane] = cn;
    h_tr[(size_t)lane * 512 + hglob] = hn;      // fp32 h for k23 GEMV
    s_h[u * 64 + lane] = hn;
    __syncthreads();
    if (tid < 256) {
      int q = tid >> 6;
      float h0 = s_h[(2 * q) * 64 + lane], h1 = s_h[(2 * q + 1) * 64 + lane];
      int kp = 160 + 256 * (par ^ 1) + blk * 4 + q;
      A2[(size_t)kp * 64 + lane] = packbf(h0, h1);
    }
  } else {
    int j = orow - 2048;
    out[((size_t)lane * TT + (t - 1)) * DD + j] = sigf(acc0 + out_b[j]);
  }
}

// ============ K23: head GEMV + per-batch memory phase (LDS mem, fused sweeps) ====
// LDS mem layout: row*32 uints; 16B-unit rotation: global unit g at slot (g+row)&7.
__global__ __launch_bounds__(1024) void k23(
    int t, const float* __restrict__ x, const uint_t* __restrict__ W2h,
    const float* __restrict__ read_b, const float* __restrict__ write_b,
    const float* __restrict__ h_tr,
    ushort_t* __restrict__ g_mem, uint_t* __restrict__ A2,
    float* __restrict__ g_ws) {
  const int b = blockIdx.x, tid = threadIdx.x;
  const int lane = tid & 63, wave = tid >> 6;
  extern __shared__ uint_t s_mem[];            // 131072 B
  __shared__ alignas(16) float s_proj[1088];   // all head projections
  __shared__ alignas(16) float s_eall[256];    // sigmoid(e) for 4 heads
  __shared__ float s_kk[8];                    // key norm^2 per slot
  __shared__ alignas(16) float s_h[512];
  __shared__ alignas(16) float s_wgA[1024];    // wgR, then wR final
  __shared__ alignas(16) float s_wgB[1024];    // wgW (shift stage only)
  __shared__ alignas(16) float s_part[1024];
  __shared__ alignas(16) float s_reads[RR * VV];
  __shared__ float s_redR[16];
  __shared__ float s_redW[16];
  uint_t* m32 = (uint_t*)(g_mem + (size_t)b * (NN * VV));

  // ---- load h (fp32, coalesced) ----
  if (tid < 512) s_h[tid] = h_tr[(size_t)b * 512 + tid];
  __syncthreads();

  // ---- head-projection GEMV: 1072 rows, 4 threads/row ----
  {
    const int sub = tid & 3;
    #pragma unroll
    for (int pp = 0; pp < 5; ++pp) {
      int r = pp * 256 + (tid >> 2);
      if (r < 1072) {
        const uint4* w4 = (const uint4*)(W2h + (size_t)r * 256);
        float acc = 0.f;
        #pragma unroll
        for (int i = 0; i < 16; ++i) {
          uint4 w = w4[sub + 4 * i];
          const float4* hh = (const float4*)s_h + (sub + 4 * i) * 2;
          acc += dot8bf(w, hh[0], hh[1]);
        }
        acc += __shfl_xor(acc, 1); acc += __shfl_xor(acc, 2);
        if (sub == 0) s_proj[r] = acc + (r < 280 ? read_b[r] : write_b[r - 280]);
      }
    }
  }
  __syncthreads();

  // ---- e (sigmoid) for all heads + key norms (8 slots by waves 0..7) ----
  if (tid < 256) s_eall[tid] = sigf(s_proj[280 + (tid >> 6) * 198 + 70 + (tid & 63)]);
  if (wave < 8) {
    int base = (wave & 1) ? (280 + (wave >> 1) * 198) : ((wave >> 1) * 70);
    float v = s_proj[base + lane];
    v = v * v;
    #pragma unroll
    for (int o = 32; o; o >>= 1) v += __shfl_xor(v, o);
    if (lane == 0) s_kk[wave] = v;
  }
  __syncthreads();

  // ---- initial global->LDS load + dot/nrm for head 0 (thread = row) ----
  float dotR = 0.f, dotW = 0.f, nrm2 = 0.f;
  {
    const uint4* rowp = (const uint4*)m32 + tid * 8;
    uint4* srow = (uint4*)(s_mem + tid * 32);
    const float2* krp = (const float2*)(s_proj);
    const float2* kwp = (const float2*)(s_proj + 280);
    #pragma unroll
    for (int g = 0; g < 8; ++g) {
      uint4 m = rowp[g];
      srow[(g + tid) & 7] = m;
      const uint_t* pm = (const uint_t*)&m;
      #pragma unroll
      for (int jj = 0; jj < 4; ++jj) {
        float v0 = bflo(pm[jj]), v1 = bfhi(pm[jj]);
        float2 kr = krp[g * 4 + jj];
        float2 kw = kwp[g * 4 + jj];
        nrm2 += v0 * v0 + v1 * v1;
        dotR += v0 * kr.x + v1 * kr.y;
        dotW += v0 * kw.x + v1 * kw.y;
      }
    }
  }

  #pragma unroll
  for (int hd = 0; hd < RR; ++hd) {
    const int kbR = hd * 70, kbW = 280 + hd * 198;
    float wprevR = g_ws[(size_t)(b * 8 + 2 * hd) * 1024 + tid];
    float wprevW = g_ws[(size_t)(b * 8 + 2 * hd + 1) * 1024 + tid];

    // ---- dual softmax chain (scalars from s_proj, kk from s_kk) ----
    float na = fmaxf(sqrtf(nrm2), 1e-8f);
    float nbR = fmaxf(sqrtf(s_kk[2 * hd]), 1e-8f);
    float nbW = fmaxf(sqrtf(s_kk[2 * hd + 1]), 1e-8f);
    float betaR = splus(s_proj[kbR + 64]), betaW = splus(s_proj[kbW + 64]);
    float gR = sigf(s_proj[kbR + 65]), gW = sigf(s_proj[kbW + 65]);
    float r0 = s_proj[kbR + 66], r1 = s_proj[kbR + 67], r2 = s_proj[kbR + 68];
    float q0 = s_proj[kbW + 66], q1 = s_proj[kbW + 67], q2 = s_proj[kbW + 68];
    float mxR = fmaxf(r0, fmaxf(r1, r2)), mxW = fmaxf(q0, fmaxf(q1, q2));
    float eR0 = __expf(r0 - mxR), eR1 = __expf(r1 - mxR), eR2 = __expf(r2 - mxR);
    float eW0 = __expf(q0 - mxW), eW1 = __expf(q1 - mxW), eW2 = __expf(q2 - mxW);
    float siR = 1.0f / (eR0 + eR1 + eR2), siW = 1.0f / (eW0 + eW1 + eW2);
    float gamR = 1.0f + splus(s_proj[kbR + 69]), gamW = 1.0f + splus(s_proj[kbW + 69]);
    float eeR = __expf(betaR * dotR / (na * nbR));   // |z|<=beta: no max-sub
    float eeW = __expf(betaW * dotW / (na * nbW));
    float vR = eeR, vW = eeW;
    #pragma unroll
    for (int o = 32; o; o >>= 1) { vR += __shfl_xor(vR, o); vW += __shfl_xor(vW, o); }
    if (lane == 0) { s_redR[wave] = vR; s_redW[wave] = vW; }
    __syncthreads();                              // S1
    float SR = 0.f, SW = 0.f;
    #pragma unroll
    for (int w = 0; w < 16; ++w) { SR += s_redR[w]; SW += s_redW[w]; }
    float wgR = gR * (eeR / SR) + (1.0f - gR) * wprevR;
    float wgW = gW * (eeW / SW) + (1.0f - gW) * wprevW;
    s_wgA[tid] = wgR;
    s_wgB[tid] = wgW;
    __syncthreads();                              // S2
    int tm = (tid + 1023) & 1023, tp = (tid + 1) & 1023;
    float wsnR = (eR0 * siR) * s_wgA[tm] + (eR1 * siR) * s_wgA[tid] + (eR2 * siR) * s_wgA[tp];
    float wsnW = (eW0 * siW) * s_wgB[tm] + (eW1 * siW) * s_wgB[tid] + (eW2 * siW) * s_wgB[tp];
    float wpR = __expf(gamR * __logf(wsnR));
    float wpW = __expf(gamW * __logf(wsnW));
    vR = wpR; vW = wpW;
    #pragma unroll
    for (int o = 32; o; o >>= 1) { vR += __shfl_xor(vR, o); vW += __shfl_xor(vW, o); }
    if (lane == 0) { s_redR[wave] = vR; s_redW[wave] = vW; }
    __syncthreads();                              // S3
    float ZR = 0.f, ZW = 0.f;
    #pragma unroll
    for (int w = 0; w < 16; ++w) { ZR += s_redR[w]; ZW += s_redW[w]; }
    float wRf = wpR / (ZR + 1e-16f);
    float wWf = wpW / (ZW + 1e-16f);
    s_wgA[tid] = wRf;
    g_ws[(size_t)(b * 8 + 2 * hd) * 1024 + tid] = wRf;
    g_ws[(size_t)(b * 8 + 2 * hd + 1) * 1024 + tid] = wWf;
    __syncthreads();                              // S4: wR visible

    // ---- sweep1: einsum (column-major, read-only, pre-erase) ----
    {
      const int cp = lane & 31, half = lane >> 5;
      const int rbase = wave * 64 + half;
      const int unit_off = (cp & 3);
      float acc0 = 0.f, acc1 = 0.f;
      #pragma unroll 8
      for (int q = 0; q < 32; ++q) {
        int row = rbase + 2 * q;
        int addr = row * 32 + (((cp >> 2) + row) & 7) * 4 + unit_off;
        uint_t uu = s_mem[addr];
        float wRn = s_wgA[row];
        acc0 += wRn * bflo(uu);
        acc1 += wRn * bfhi(uu);
      }
      acc0 += __shfl_xor(acc0, 32);
      acc1 += __shfl_xor(acc1, 32);
      if (half == 0) *(float2*)(s_part + wave * 64 + 2 * cp) = make_float2(acc0, acc1);
    }
    __syncthreads();                              // S5

    // ---- sweep2: erase (row-major) + dot/nrm for head hd+1 ----
    {
      const int row = tid;
      uint4* srow = (uint4*)(s_mem + row * 32);
      const float2* ep = (const float2*)(s_eall + hd * 64);
      const float2* ap = (const float2*)(s_proj + kbW + 134);
      const float2* krn = (const float2*)(s_proj + (hd + 1) * 70);
      const float2* kwn = (const float2*)(s_proj + 280 + (hd + 1) * 198);
      float dR = 0.f, dW = 0.f, nn = 0.f;
      #pragma unroll
      for (int g = 0; g < 8; ++g) {
        uint4 m = srow[(g + row) & 7];
        const uint_t* pm = (const uint_t*)&m;
        uint4 nu;
        uint_t* pn = (uint_t*)&nu;
        #pragma unroll
        for (int jj = 0; jj < 4; ++jj) {
          float v0 = bflo(pm[jj]), v1 = bfhi(pm[jj]);
          float2 ev = ep[g * 4 + jj];
          float2 av = ap[g * 4 + jj];
          float n0 = v0 * (1.f - wWf * ev.x) + wWf * av.x;
          float n1 = v1 * (1.f - wWf * ev.y) + wWf * av.y;
          pn[jj] = packbf(n0, n1);
          if (hd < 3) {
            float2 kr = krn[g * 4 + jj];
            float2 kw = kwn[g * 4 + jj];
            dR += n0 * kr.x + n1 * kr.y;
            dW += n0 * kw.x + n1 * kw.y;
            nn += n0 * n0 + n1 * n1;
          }
        }
        if (hd < 3) srow[(g + row) & 7] = nu;
        else        ((uint4*)m32)[row * 8 + g] = nu;   // final mem -> global
      }
      dotR = dR; dotW = dW; nrm2 = nn;
    }
    // combine einsum partials (s_part stable since S5)
    if (tid < VV) {
      float s = 0.f;
      #pragma unroll
      for (int w2 = 0; w2 < 16; ++w2) s += s_part[w2 * 64 + tid];
      s_reads[hd * VV + tid] = s;
    }
    __syncthreads();                              // S6
  } // hd

  // ---- publish reads_t and x_{t+1} into A2 (bf16 pairs) ----
  if (tid < 128)
    A2[(size_t)(32 + tid) * 64 + b] = packbf(s_reads[2 * tid], s_reads[2 * tid + 1]);
  if (tid < 32 && t + 1 < TT) {
    float v0 = x[((size_t)b * TT + t + 1) * DD + 2 * tid];
    float v1 = x[((size_t)b * TT + t + 1) * DD + 2 * tid + 1];
    A2[(size_t)tid * 64 + b] = packbf(v0, v1);
  }
}

extern "C" void kernel_launch(void* const* d_in, const int* in_sizes, int n_in,
                              void* d_out, int out_size, void* d_ws, size_t ws_size,
                              hipStream_t stream) {
  char* ws = (char*)d_ws;
  ushort_t* g_mem = (ushort_t*)ws;                 //  8,388,608
  uint_t* g_A2    = (uint_t*)(ws + 8388608);       //    172,032
  float* g_c      = (float*)(ws + 8560640);        //    131,072
  float* g_ws     = (float*)(ws + 8691712);        //  2,097,152
  float* h_tr     = (float*)(ws + 10788864);       //    131,072
  uint_t* W2g     = (uint_t*)(ws + 10919936);      //  3,514,368
  uint_t* W2h     = (uint_t*)(ws + 14434304);      //  1,097,728
  float* gbias    = (float*)(ws + 15532032);       //      8,192  (~15.5 MB)

  const float* x        = (const float*)d_in[0];
  const float* mem_bias = (const float*)d_in[1];
  const float* h_bias   = (const float*)d_in[2];
  const float* c_bias   = (const float*)d_in[3];
  const float* W_ih     = (const float*)d_in[4];
  const float* W_hh     = (const float*)d_in[5];
  const float* b_ih     = (const float*)d_in[6];
  const float* b_hh     = (const float*)d_in[7];
  const float* read_W   = (const float*)d_in[8];
  const float* read_b   = (const float*)d_in[9];
  const float* write_W  = (const float*)d_in[10];
  const float* write_b  = (const float*)d_in[11];
  const float* read_init= (const float*)d_in[12];
  const float* out_W    = (const float*)d_in[13];
  const float* out_b    = (const float*)d_in[14];
  float* out = (float*)d_out;

  bias_kernel<<<8, 256, 0, stream>>>(b_ih, b_hh, gbias);
  build_gw<<<3432, 256, 0, stream>>>(W_ih, W_hh, out_W, W2g);
  build_hw<<<1072, 256, 0, stream>>>(read_W, write_W, W2h);
  k0_init<<<64, 1024, 0, stream>>>(x, mem_bias, h_bias, c_bias, read_init,
                                   g_mem, g_A2, g_c, g_ws);
  for (int t = 0; t < TT; ++t) {
    k1_gates<<<72, 512, 0, stream>>>(t, 64, t & 1, W2g, gbias, g_A2, g_c, out_b, out, h_tr);
    k23<<<64, 1024, 131072, stream>>>(t, x, W2h, read_b, write_b, h_tr, g_mem, g_A2, g_ws);
  }
  // final out row batch: out(t=31) from h_31 (slot 0) + reads_31
  k1_gates<<<8, 512, 0, stream>>>(TT, 0, 0, W2g, gbias, g_A2, g_c, out_b, out, h_tr);
}

// Round 13
// 6579.237 us; speedup vs baseline: 1.0235x; 1.0235x over previous
//
#include <hip/hip_runtime.h>
#include <math.h>

#define TT 32
#define DD 64
#define NN 1024
#define VV 64
#define RR 4
#define HH 512

typedef unsigned int uint_t;
typedef unsigned short ushort_t;

__device__ __forceinline__ float sigf(float x) { return 1.0f / (1.0f + __expf(-x)); }
__device__ __forceinline__ float splus(float x) {
  return (x > 0.f) ? (x + log1pf(__expf(-x))) : log1pf(__expf(x));
}
__device__ __forceinline__ ushort_t bfr(float f) {
  uint_t u = __float_as_uint(f);
  return (ushort_t)((u + 0x7fffu + ((u >> 16) & 1u)) >> 16);
}
__device__ __forceinline__ float bflo(uint_t u) { return __uint_as_float(u << 16); }
__device__ __forceinline__ float bfhi(uint_t u) { return __uint_as_float(u & 0xffff0000u); }
__device__ __forceinline__ uint_t packbf(float a, float b) {
  return (uint_t)bfr(a) | ((uint_t)bfr(b) << 16);
}

// ============ pre-kernels (every launch; deterministic) ============
__global__ void build_gw(const float* __restrict__ W_ih, const float* __restrict__ W_hh,
                         const float* __restrict__ out_W, uint_t* __restrict__ W2g) {
  int idx = blockIdx.x * 256 + threadIdx.x;           // 2112*416
  if (idx >= 2112 * 416) return;
  int r = idx / 416, kp = idx - r * 416;
  float v[2];
  #pragma unroll
  for (int q = 0; q < 2; ++q) {
    int k = 2 * kp + q;
    float f;
    if (r < 2048) {
      int h = r >> 2, g = r & 3, row = g * 512 + h;
      f = (k < 320) ? W_ih[(size_t)row * 320 + k] : W_hh[(size_t)row * 512 + (k - 320)];
    } else {
      int j = r - 2048;
      if (k < 64) f = 0.f;
      else if (k < 320) f = out_W[(size_t)j * 768 + 512 + (k - 64)];
      else f = out_W[(size_t)j * 768 + (k - 320)];
    }
    v[q] = f;
  }
  W2g[idx] = packbf(v[0], v[1]);
}
__global__ void build_hw(const float* __restrict__ read_W, const float* __restrict__ write_W,
                         uint_t* __restrict__ W2h) {
  int idx = blockIdx.x * 256 + threadIdx.x;           // 1072*256
  if (idx >= 1072 * 256) return;
  int r = idx >> 8, kp = idx & 255;
  const float* src = (r < 280) ? (read_W + (size_t)r * 512) : (write_W + (size_t)(r - 280) * 512);
  W2h[idx] = packbf(src[2 * kp], src[2 * kp + 1]);
}
__global__ void bias_kernel(const float* __restrict__ bi, const float* __restrict__ bh,
                            float* __restrict__ o) {
  int i = blockIdx.x * 256 + threadIdx.x;
  if (i < 2048) o[i] = bi[i] + bh[i];
}
__global__ void k0_init(const float* __restrict__ x, const float* __restrict__ mem_bias,
                        const float* __restrict__ h_bias, const float* __restrict__ c_bias,
                        const float* __restrict__ read_init,
                        ushort_t* __restrict__ g_mem, uint_t* __restrict__ A2,
                        float* __restrict__ g_c, float* __restrict__ g_ws) {
  const int b = blockIdx.x, tid = threadIdx.x;
  {
    const float4* src = (const float4*)(mem_bias + (size_t)tid * VV);
    uint4* dst = (uint4*)(g_mem + (size_t)b * (NN * VV) + (size_t)tid * VV);
    #pragma unroll
    for (int p = 0; p < 8; ++p) {
      float4 va = src[2 * p], vb = src[2 * p + 1];
      uint4 o;
      o.x = packbf(va.x, va.y); o.y = packbf(va.z, va.w);
      o.z = packbf(vb.x, vb.y); o.w = packbf(vb.z, vb.w);
      dst[p] = o;
    }
  }
  if (tid < 416) {
    float v0, v1;
    if (tid < 32)      { v0 = x[((size_t)b * TT) * DD + 2 * tid]; v1 = x[((size_t)b * TT) * DD + 2 * tid + 1]; }
    else if (tid < 160){ int e = 2 * (tid - 32); v0 = read_init[e]; v1 = read_init[e + 1]; }
    else               { int e = 2 * (tid - 160); v0 = h_bias[e]; v1 = h_bias[e + 1]; }
    A2[(size_t)tid * 64 + b] = packbf(v0, v1);
  }
  if (tid < 512) g_c[(size_t)tid * 64 + b] = c_bias[tid];
  for (int i = tid; i < 8192; i += 1024) g_ws[(size_t)b * 8192 + i] = 0.f;
}

// ============ K1: gates GEMM + LSTM + out(t-1) rows ============
__global__ __launch_bounds__(512) void k1_gates(
    int t, int nGate, int par,
    const uint_t* __restrict__ W2g, const float* __restrict__ gbias,
    uint_t* __restrict__ A2, float* __restrict__ g_c,
    const float* __restrict__ out_b, float* __restrict__ out) {
  const int blk = blockIdx.x, tid = threadIdx.x;
  const int lane = tid & 63, u = tid >> 6;
  const bool isGate = (blk < nGate);
  if (!isGate && t == 0) return;
  __shared__ uint_t s_tile[52 * 64];
  __shared__ float s_h[8 * 64];
  float acc0 = 0.f, acc1 = 0.f, acc2 = 0.f, acc3 = 0.f;
  const int hglob = blk * 8 + u;
  const int orow = 2048 + (blk - nGate) * 8 + u;
  const size_t wbase = isGate ? (size_t)(hglob * 4) * 416 : (size_t)orow * 416;

  for (int c = 0; c < 8; ++c) {
    for (int i = tid; i < 52 * 64; i += 512) {
      int kk = i >> 6, bb = i & 63;
      int kpg = c * 52 + kk;
      int phys = (kpg < 160) ? kpg : kpg + 256 * par;
      s_tile[i] = A2[(size_t)phys * 64 + bb];
    }
    __syncthreads();
    const uint4* w4 = (const uint4*)(W2g + wbase) + c * 13;
    if (isGate) {
      #pragma unroll
      for (int q = 0; q < 13; ++q) {
        uint4 wA = w4[q], wB = w4[104 + q], wC = w4[208 + q], wD = w4[312 + q];
        const uint_t* pA = (const uint_t*)&wA;
        const uint_t* pB = (const uint_t*)&wB;
        const uint_t* pC = (const uint_t*)&wC;
        const uint_t* pD = (const uint_t*)&wD;
        #pragma unroll
        for (int jj = 0; jj < 4; ++jj) {
          uint_t ua = s_tile[(q * 4 + jj) * 64 + lane];
          float a0 = bflo(ua), a1 = bfhi(ua);
          acc0 += bflo(pA[jj]) * a0 + bfhi(pA[jj]) * a1;
          acc1 += bflo(pB[jj]) * a0 + bfhi(pB[jj]) * a1;
          acc2 += bflo(pC[jj]) * a0 + bfhi(pC[jj]) * a1;
          acc3 += bflo(pD[jj]) * a0 + bfhi(pD[jj]) * a1;
        }
      }
    } else {
      #pragma unroll
      for (int q = 0; q < 13; ++q) {
        uint4 wA = w4[q];
        const uint_t* pA = (const uint_t*)&wA;
        #pragma unroll
        for (int jj = 0; jj < 4; ++jj) {
          uint_t ua = s_tile[(q * 4 + jj) * 64 + lane];
          acc0 += bflo(pA[jj]) * bflo(ua) + bfhi(pA[jj]) * bfhi(ua);
        }
      }
    }
    __syncthreads();
  }

  if (isGate) {
    float gi = acc0 + gbias[hglob];
    float gf = acc1 + gbias[512 + hglob];
    float gg = acc2 + gbias[1024 + hglob];
    float go = acc3 + gbias[1536 + hglob];
    float c0 = g_c[(size_t)hglob * 64 + lane];
    float cn = sigf(gf) * c0 + sigf(gi) * tanhf(gg);
    float hn = sigf(go) * tanhf(cn);
    g_c[(size_t)hglob * 64 + lane] = cn;
    s_h[u * 64 + lane] = hn;
    __syncthreads();
    if (tid < 256) {
      int q = tid >> 6;
      float h0 = s_h[(2 * q) * 64 + lane], h1 = s_h[(2 * q + 1) * 64 + lane];
      int kp = 160 + 256 * (par ^ 1) + blk * 4 + q;
      A2[(size_t)kp * 64 + lane] = packbf(h0, h1);
    }
  } else {
    int j = orow - 2048;
    out[((size_t)lane * TT + (t - 1)) * DD + j] = sigf(acc0 + out_b[j]);
  }
}

// ============ K2: head projections GEMM (weight-stationary; proven) ============
__global__ __launch_bounds__(512) void k2_heads(
    int wslot, const uint_t* __restrict__ W2h,
    const float* __restrict__ read_b, const float* __restrict__ write_b,
    const uint_t* __restrict__ A2, float* __restrict__ g_headp) {
  const int blk = blockIdx.x, tid = threadIdx.x;
  const int lane = tid & 63, u = tid >> 6;
  const int r = blk * 8 + u;
  __shared__ uint_t s_tile[64 * 64];
  __shared__ float s_tr[8 * 65];
  const int hbase = 160 + 256 * wslot;
  float acc = 0.f;
  const uint_t* wrow = W2h + (size_t)r * 256;
  for (int c = 0; c < 4; ++c) {
    for (int i = tid; i < 64 * 64; i += 512) {
      int kk = i >> 6, bb = i & 63;
      s_tile[i] = A2[(size_t)(hbase + c * 64 + kk) * 64 + bb];
    }
    __syncthreads();
    #pragma unroll 4
    for (int kk = 0; kk < 64; ++kk) {
      uint_t ua = s_tile[kk * 64 + lane];
      uint_t w = wrow[c * 64 + kk];
      acc += bflo(w) * bflo(ua) + bfhi(w) * bfhi(ua);
    }
    __syncthreads();
  }
  acc += (r < 280) ? read_b[r] : write_b[r - 280];
  s_tr[u * 65 + lane] = acc;
  __syncthreads();
  if (tid < 128) {
    int bb = tid & 63, half = tid >> 6;
    float4 v;
    v.x = s_tr[(half * 4 + 0) * 65 + bb];
    v.y = s_tr[(half * 4 + 1) * 65 + bb];
    v.z = s_tr[(half * 4 + 2) * 65 + bb];
    v.w = s_tr[(half * 4 + 3) * 65 + bb];
    *(float4*)(g_headp + (size_t)bb * 1088 + blk * 8 + half * 4) = v;
  }
}

// ============ K3: per-batch memory phase — LDS mem, 2 sweeps/head ============
// LDS layout: row*32 uints; 16B-unit rotation: global unit g stored at slot (g+row)&7.
__global__ __launch_bounds__(1024) void k3_mem(
    int t, const float* __restrict__ x, const float* __restrict__ g_headp,
    ushort_t* __restrict__ g_mem, uint_t* __restrict__ A2,
    float* __restrict__ g_ws) {
  const int b = blockIdx.x, tid = threadIdx.x;
  const int lane = tid & 63, wave = tid >> 6;
  extern __shared__ uint_t s_mem[];            // 131072 B
  __shared__ alignas(16) float s_proj[1088];   // all head projections (bias folded)
  __shared__ alignas(16) float s_eall[256];    // sigmoid(e), 4 heads
  __shared__ float s_kk[8];                    // key |k|^2 per slot
  __shared__ alignas(16) float s_wgA[1024];    // wgR, then wR final
  __shared__ alignas(16) float s_wgB[1024];    // wgW, then wW final
  __shared__ alignas(16) float s_part[1024];
  __shared__ alignas(16) float s_reads[RR * VV];
  __shared__ float s_redR[16];
  __shared__ float s_redW[16];
  uint_t* m32 = (uint_t*)(g_mem + (size_t)b * (NN * VV));
  const float* hp = g_headp + (size_t)b * 1088;

  // ---- prefetch ws history (8 slots) into registers (latency hidden) ----
  float wsr[8];
  #pragma unroll
  for (int s2 = 0; s2 < 8; ++s2) wsr[s2] = g_ws[(size_t)(b * 8 + s2) * 1024 + tid];

  // ---- stage all projections ----
  for (int i = tid; i < 1072; i += 1024) s_proj[i] = hp[i];
  __syncthreads();
  // e-sigmoids + key norms (visible after S1 of head 0)
  if (tid < 256) s_eall[tid] = sigf(s_proj[280 + (tid >> 6) * 198 + 70 + (tid & 63)]);
  if (wave < 8) {
    int base = (wave & 1) ? (280 + (wave >> 1) * 198) : ((wave >> 1) * 70);
    float v = s_proj[base + lane];
    v = v * v;
    #pragma unroll
    for (int o = 32; o; o >>= 1) v += __shfl_xor(v, o);
    if (lane == 0) s_kk[wave] = v;
  }

  // ---- initial global->LDS + head-0 dot/nrm (thread = row) ----
  float dotR = 0.f, dotW = 0.f, nrm2 = 0.f;
  {
    const uint4* rowp = (const uint4*)m32 + tid * 8;
    uint4* srow = (uint4*)(s_mem + tid * 32);
    const float2* krp = (const float2*)(s_proj);
    const float2* kwp = (const float2*)(s_proj + 280);
    #pragma unroll
    for (int g = 0; g < 8; ++g) {
      uint4 m = rowp[g];
      srow[(g + tid) & 7] = m;
      const uint_t* pm = (const uint_t*)&m;
      #pragma unroll
      for (int jj = 0; jj < 4; ++jj) {
        float v0 = bflo(pm[jj]), v1 = bfhi(pm[jj]);
        float2 kr = krp[g * 4 + jj];
        float2 kw = kwp[g * 4 + jj];
        nrm2 += v0 * v0 + v1 * v1;
        dotR += v0 * kr.x + v1 * kr.y;
        dotW += v0 * kw.x + v1 * kw.y;
      }
    }
  }

  #pragma unroll
  for (int hd = 0; hd < RR; ++hd) {
    const int kbR = hd * 70, kbW = 280 + hd * 198;

    // ---- dual softmax chain ----
    float na = fmaxf(sqrtf(nrm2), 1e-8f);
    float nbR = fmaxf(sqrtf(s_kk[2 * hd]), 1e-8f);
    float nbW = fmaxf(sqrtf(s_kk[2 * hd + 1]), 1e-8f);
    float betaR = splus(s_proj[kbR + 64]), betaW = splus(s_proj[kbW + 64]);
    float gR = sigf(s_proj[kbR + 65]), gW = sigf(s_proj[kbW + 65]);
    float r0 = s_proj[kbR + 66], r1 = s_proj[kbR + 67], r2 = s_proj[kbR + 68];
    float q0 = s_proj[kbW + 66], q1 = s_proj[kbW + 67], q2 = s_proj[kbW + 68];
    float mxR = fmaxf(r0, fmaxf(r1, r2)), mxW = fmaxf(q0, fmaxf(q1, q2));
    float eR0 = __expf(r0 - mxR), eR1 = __expf(r1 - mxR), eR2 = __expf(r2 - mxR);
    float eW0 = __expf(q0 - mxW), eW1 = __expf(q1 - mxW), eW2 = __expf(q2 - mxW);
    float siR = 1.0f / (eR0 + eR1 + eR2), siW = 1.0f / (eW0 + eW1 + eW2);
    float gamR = 1.0f + splus(s_proj[kbR + 69]), gamW = 1.0f + splus(s_proj[kbW + 69]);
    float eeR = __expf(betaR * dotR / (na * nbR));   // |z|<=beta: no max-sub
    float eeW = __expf(betaW * dotW / (na * nbW));
    float vR = eeR, vW = eeW;
    #pragma unroll
    for (int o = 32; o; o >>= 1) { vR += __shfl_xor(vR, o); vW += __shfl_xor(vW, o); }
    if (lane == 0) { s_redR[wave] = vR; s_redW[wave] = vW; }
    __syncthreads();                              // S1
    float SR = 0.f, SW = 0.f;
    #pragma unroll
    for (int w = 0; w < 16; ++w) { SR += s_redR[w]; SW += s_redW[w]; }
    float wgR = gR * (eeR / SR) + (1.0f - gR) * wsr[2 * hd];
    float wgW = gW * (eeW / SW) + (1.0f - gW) * wsr[2 * hd + 1];
    s_wgA[tid] = wgR;
    s_wgB[tid] = wgW;
    __syncthreads();                              // S2
    int tm = (tid + 1023) & 1023, tp = (tid + 1) & 1023;
    float wsnR = (eR0 * siR) * s_wgA[tm] + (eR1 * siR) * s_wgA[tid] + (eR2 * siR) * s_wgA[tp];
    float wsnW = (eW0 * siW) * s_wgB[tm] + (eW1 * siW) * s_wgB[tid] + (eW2 * siW) * s_wgB[tp];
    float wpR = __expf(gamR * __logf(wsnR));
    float wpW = __expf(gamW * __logf(wsnW));
    vR = wpR; vW = wpW;
    #pragma unroll
    for (int o = 32; o; o >>= 1) { vR += __shfl_xor(vR, o); vW += __shfl_xor(vW, o); }
    if (lane == 0) { s_redR[wave] = vR; s_redW[wave] = vW; }
    __syncthreads();                              // S3
    float ZR = 0.f, ZW = 0.f;
    #pragma unroll
    for (int w = 0; w < 16; ++w) { ZR += s_redR[w]; ZW += s_redW[w]; }
    float wRf = wpR / (ZR + 1e-16f);
    float wWf = wpW / (ZW + 1e-16f);
    wsr[2 * hd] = wRf;
    wsr[2 * hd + 1] = wWf;
    s_wgA[tid] = wRf;
    s_wgB[tid] = wWf;
    g_ws[(size_t)(b * 8 + 2 * hd) * 1024 + tid] = wRf;
    g_ws[(size_t)(b * 8 + 2 * hd + 1) * 1024 + tid] = wWf;
    __syncthreads();                              // S4: wR/wW visible

    if (hd < 3) {
      // ---- sweep1: einsum, column-major (pre-erase) ----
      {
        const int cp = lane & 31, half = lane >> 5;
        const int rbase = wave * 64 + half;
        float acc0 = 0.f, acc1 = 0.f;
        #pragma unroll 8
        for (int q = 0; q < 32; ++q) {
          int row = rbase + 2 * q;
          int addr = row * 32 + (((cp >> 2) + row) & 7) * 4 + (cp & 3);
          uint_t uu = s_mem[addr];
          float wRn = s_wgA[row];
          acc0 += wRn * bflo(uu);
          acc1 += wRn * bfhi(uu);
        }
        acc0 += __shfl_xor(acc0, 32);
        acc1 += __shfl_xor(acc1, 32);
        if (half == 0) *(float2*)(s_part + wave * 64 + 2 * cp) = make_float2(acc0, acc1);
      }
      __syncthreads();                            // S5: einsum reads done
      // ---- sweep2: erase row-major in LDS + next head's dot/nrm (fused) ----
      {
        const int row = tid;
        uint4* srow = (uint4*)(s_mem + row * 32);
        const float2* ep = (const float2*)(s_eall + hd * 64);
        const float2* ap = (const float2*)(s_proj + kbW + 134);
        const float2* krn = (const float2*)(s_proj + (hd + 1) * 70);
        const float2* kwn = (const float2*)(s_proj + 280 + (hd + 1) * 198);
        float dR = 0.f, dW = 0.f, nn = 0.f;
        #pragma unroll
        for (int g = 0; g < 8; ++g) {
          uint4 m = srow[(g + row) & 7];
          const uint_t* pm = (const uint_t*)&m;
          uint4 nu;
          uint_t* pn = (uint_t*)&nu;
          #pragma unroll
          for (int jj = 0; jj < 4; ++jj) {
            float v0 = bflo(pm[jj]), v1 = bfhi(pm[jj]);
            float2 ev = ep[g * 4 + jj];
            float2 av = ap[g * 4 + jj];
            float n0 = v0 * (1.f - wWf * ev.x) + wWf * av.x;
            float n1 = v1 * (1.f - wWf * ev.y) + wWf * av.y;
            pn[jj] = packbf(n0, n1);
            float2 kr = krn[g * 4 + jj];
            float2 kw = kwn[g * 4 + jj];
            dR += n0 * kr.x + n1 * kr.y;
            dW += n0 * kw.x + n1 * kw.y;
            nn += n0 * n0 + n1 * n1;
          }
          srow[(g + row) & 7] = nu;
        }
        dotR = dR; dotW = dW; nrm2 = nn;
      }
    } else {
      // ---- hd=3: fused einsum + erase, column-major; final mem -> global (NT) ----
      const int cp = lane & 31, half = lane >> 5;
      const float e0 = s_eall[192 + 2 * cp], e1 = s_eall[192 + 2 * cp + 1];
      const float a0 = s_proj[kbW + 134 + 2 * cp], a1 = s_proj[kbW + 134 + 2 * cp + 1];
      const int rbase = wave * 64 + half;
      float acc0 = 0.f, acc1 = 0.f;
      #pragma unroll 8
      for (int q = 0; q < 32; ++q) {
        int row = rbase + 2 * q;
        int addr = row * 32 + (((cp >> 2) + row) & 7) * 4 + (cp & 3);
        uint_t uu = s_mem[addr];
        float wRn = s_wgA[row];
        float wWn = s_wgB[row];
        float v0 = bflo(uu), v1 = bfhi(uu);
        acc0 += wRn * v0;
        acc1 += wRn * v1;
        float n0 = v0 * (1.f - wWn * e0) + wWn * a0;
        float n1 = v1 * (1.f - wWn * e1) + wWn * a1;
        __builtin_nontemporal_store(packbf(n0, n1), &m32[(size_t)row * 32 + cp]);
      }
      acc0 += __shfl_xor(acc0, 32);
      acc1 += __shfl_xor(acc1, 32);
      if (half == 0) *(float2*)(s_part + wave * 64 + 2 * cp) = make_float2(acc0, acc1);
      __syncthreads();                            // S5
    }
    // combine einsum partials -> s_reads (s_part stable since S5)
    if (tid < VV) {
      float s = 0.f;
      #pragma unroll
      for (int w2 = 0; w2 < 16; ++w2) s += s_part[w2 * 64 + tid];
      s_reads[hd * VV + tid] = s;
    }
  } // hd
  __syncthreads();

  // ---- publish reads_t and x_{t+1} into A2 (bf16 pairs) ----
  if (tid < 128)
    A2[(size_t)(32 + tid) * 64 + b] = packbf(s_reads[2 * tid], s_reads[2 * tid + 1]);
  if (tid < 32 && t + 1 < TT) {
    float v0 = x[((size_t)b * TT + t + 1) * DD + 2 * tid];
    float v1 = x[((size_t)b * TT + t + 1) * DD + 2 * tid + 1];
    A2[(size_t)tid * 64 + b] = packbf(v0, v1);
  }
}

extern "C" void kernel_launch(void* const* d_in, const int* in_sizes, int n_in,
                              void* d_out, int out_size, void* d_ws, size_t ws_size,
                              hipStream_t stream) {
  char* ws = (char*)d_ws;
  ushort_t* g_mem = (ushort_t*)ws;                 //  8,388,608
  uint_t* g_A2    = (uint_t*)(ws + 8388608);       //    172,032
  float* g_c      = (float*)(ws + 8560640);        //    131,072
  float* g_ws     = (float*)(ws + 8691712);        //  2,097,152
  float* g_headp  = (float*)(ws + 10788864);       //    278,528
  uint_t* W2g     = (uint_t*)(ws + 11067392);      //  3,514,368
  uint_t* W2h     = (uint_t*)(ws + 14581760);      //  1,097,728
  float* gbias    = (float*)(ws + 15679488);       //      8,192  (~15.7 MB)

  const float* x        = (const float*)d_in[0];
  const float* mem_bias = (const float*)d_in[1];
  const float* h_bias   = (const float*)d_in[2];
  const float* c_bias   = (const float*)d_in[3];
  const float* W_ih     = (const float*)d_in[4];
  const float* W_hh     = (const float*)d_in[5];
  const float* b_ih     = (const float*)d_in[6];
  const float* b_hh     = (const float*)d_in[7];
  const float* read_W   = (const float*)d_in[8];
  const float* read_b   = (const float*)d_in[9];
  const float* write_W  = (const float*)d_in[10];
  const float* write_b  = (const float*)d_in[11];
  const float* read_init= (const float*)d_in[12];
  const float* out_W    = (const float*)d_in[13];
  const float* out_b    = (const float*)d_in[14];
  float* out = (float*)d_out;

  bias_kernel<<<8, 256, 0, stream>>>(b_ih, b_hh, gbias);
  build_gw<<<3432, 256, 0, stream>>>(W_ih, W_hh, out_W, W2g);
  build_hw<<<1072, 256, 0, stream>>>(read_W, write_W, W2h);
  k0_init<<<64, 1024, 0, stream>>>(x, mem_bias, h_bias, c_bias, read_init,
                                   g_mem, g_A2, g_c, g_ws);
  for (int t = 0; t < TT; ++t) {
    k1_gates<<<72, 512, 0, stream>>>(t, 64, t & 1, W2g, gbias, g_A2, g_c, out_b, out);
    k2_heads<<<134, 512, 0, stream>>>((t + 1) & 1, W2h, read_b, write_b, g_A2, g_headp);
    k3_mem<<<64, 1024, 131072, stream>>>(t, x, g_headp, g_mem, g_A2, g_ws);
  }
  // final out row batch: out(t=31) from h_31 (slot 0) + reads_31
  k1_gates<<<8, 512, 0, stream>>>(TT, 0, 0, W2g, gbias, g_A2, g_c, out_b, out);
}

// Round 14
// 6527.348 us; speedup vs baseline: 1.0317x; 1.0079x over previous
//
#include <hip/hip_runtime.h>
#include <math.h>

#define TT 32
#define DD 64
#define NN 1024
#define VV 64
#define RR 4
#define HH 512

typedef unsigned int uint_t;
typedef unsigned short ushort_t;

__device__ __forceinline__ float sigf(float x) { return 1.0f / (1.0f + __expf(-x)); }
__device__ __forceinline__ float splus(float x) {
  return (x > 0.f) ? (x + log1pf(__expf(-x))) : log1pf(__expf(x));
}
__device__ __forceinline__ ushort_t bfr(float f) {
  uint_t u = __float_as_uint(f);
  return (ushort_t)((u + 0x7fffu + ((u >> 16) & 1u)) >> 16);
}
__device__ __forceinline__ float bflo(uint_t u) { return __uint_as_float(u << 16); }
__device__ __forceinline__ float bfhi(uint_t u) { return __uint_as_float(u & 0xffff0000u); }
__device__ __forceinline__ uint_t packbf(float a, float b) {
  return (uint_t)bfr(a) | ((uint_t)bfr(b) << 16);
}

// ============ pre-kernels (every launch; deterministic) ============
__global__ void build_gw(const float* __restrict__ W_ih, const float* __restrict__ W_hh,
                         const float* __restrict__ out_W, uint_t* __restrict__ W2g) {
  int idx = blockIdx.x * 256 + threadIdx.x;           // 2112*416
  if (idx >= 2112 * 416) return;
  int r = idx / 416, kp = idx - r * 416;
  float v[2];
  #pragma unroll
  for (int q = 0; q < 2; ++q) {
    int k = 2 * kp + q;
    float f;
    if (r < 2048) {
      int h = r >> 2, g = r & 3, row = g * 512 + h;
      f = (k < 320) ? W_ih[(size_t)row * 320 + k] : W_hh[(size_t)row * 512 + (k - 320)];
    } else {
      int j = r - 2048;
      if (k < 64) f = 0.f;
      else if (k < 320) f = out_W[(size_t)j * 768 + 512 + (k - 64)];
      else f = out_W[(size_t)j * 768 + (k - 320)];
    }
    v[q] = f;
  }
  W2g[idx] = packbf(v[0], v[1]);
}
__global__ void build_hw(const float* __restrict__ read_W, const float* __restrict__ write_W,
                         uint_t* __restrict__ W2h) {
  int idx = blockIdx.x * 256 + threadIdx.x;           // 1072*256
  if (idx >= 1072 * 256) return;
  int r = idx >> 8, kp = idx & 255;
  const float* src = (r < 280) ? (read_W + (size_t)r * 512) : (write_W + (size_t)(r - 280) * 512);
  W2h[idx] = packbf(src[2 * kp], src[2 * kp + 1]);
}
__global__ void bias_kernel(const float* __restrict__ bi, const float* __restrict__ bh,
                            float* __restrict__ o) {
  int i = blockIdx.x * 256 + threadIdx.x;
  if (i < 2048) o[i] = bi[i] + bh[i];
}
__global__ void k0_init(const float* __restrict__ x, const float* __restrict__ mem_bias,
                        const float* __restrict__ h_bias, const float* __restrict__ c_bias,
                        const float* __restrict__ read_init,
                        ushort_t* __restrict__ g_mem, uint_t* __restrict__ A2,
                        float* __restrict__ g_c, float* __restrict__ g_ws) {
  const int b = blockIdx.x, tid = threadIdx.x;
  {
    const float4* src = (const float4*)(mem_bias + (size_t)tid * VV);
    uint4* dst = (uint4*)(g_mem + (size_t)b * (NN * VV) + (size_t)tid * VV);
    #pragma unroll
    for (int p = 0; p < 8; ++p) {
      float4 va = src[2 * p], vb = src[2 * p + 1];
      uint4 o;
      o.x = packbf(va.x, va.y); o.y = packbf(va.z, va.w);
      o.z = packbf(vb.x, vb.y); o.w = packbf(vb.z, vb.w);
      dst[p] = o;
    }
  }
  if (tid < 416) {
    float v0, v1;
    if (tid < 32)      { v0 = x[((size_t)b * TT) * DD + 2 * tid]; v1 = x[((size_t)b * TT) * DD + 2 * tid + 1]; }
    else if (tid < 160){ int e = 2 * (tid - 32); v0 = read_init[e]; v1 = read_init[e + 1]; }
    else               { int e = 2 * (tid - 160); v0 = h_bias[e]; v1 = h_bias[e + 1]; }
    A2[(size_t)tid * 64 + b] = packbf(v0, v1);
  }
  if (tid < 512) g_c[(size_t)tid * 64 + b] = c_bias[tid];
  for (int i = tid; i < 8192; i += 1024) g_ws[(size_t)b * 8192 + i] = 0.f;
}

// ============ K1: gates GEMM + LSTM + out(t-1) rows ============
__global__ __launch_bounds__(512) void k1_gates(
    int t, int nGate, int par,
    const uint_t* __restrict__ W2g, const float* __restrict__ gbias,
    uint_t* __restrict__ A2, float* __restrict__ g_c,
    const float* __restrict__ out_b, float* __restrict__ out) {
  const int blk = blockIdx.x, tid = threadIdx.x;
  const int lane = tid & 63, u = tid >> 6;
  const bool isGate = (blk < nGate);
  if (!isGate && t == 0) return;
  __shared__ uint_t s_tile[52 * 64];
  __shared__ float s_h[8 * 64];
  float acc0 = 0.f, acc1 = 0.f, acc2 = 0.f, acc3 = 0.f;
  const int hglob = blk * 8 + u;
  const int orow = 2048 + (blk - nGate) * 8 + u;
  const size_t wbase = isGate ? (size_t)(hglob * 4) * 416 : (size_t)orow * 416;

  for (int c = 0; c < 8; ++c) {
    for (int i = tid; i < 52 * 64; i += 512) {
      int kk = i >> 6, bb = i & 63;
      int kpg = c * 52 + kk;
      int phys = (kpg < 160) ? kpg : kpg + 256 * par;
      s_tile[i] = A2[(size_t)phys * 64 + bb];
    }
    __syncthreads();
    const uint4* w4 = (const uint4*)(W2g + wbase) + c * 13;
    if (isGate) {
      #pragma unroll
      for (int q = 0; q < 13; ++q) {
        uint4 wA = w4[q], wB = w4[104 + q], wC = w4[208 + q], wD = w4[312 + q];
        const uint_t* pA = (const uint_t*)&wA;
        const uint_t* pB = (const uint_t*)&wB;
        const uint_t* pC = (const uint_t*)&wC;
        const uint_t* pD = (const uint_t*)&wD;
        #pragma unroll
        for (int jj = 0; jj < 4; ++jj) {
          uint_t ua = s_tile[(q * 4 + jj) * 64 + lane];
          float a0 = bflo(ua), a1 = bfhi(ua);
          acc0 += bflo(pA[jj]) * a0 + bfhi(pA[jj]) * a1;
          acc1 += bflo(pB[jj]) * a0 + bfhi(pB[jj]) * a1;
          acc2 += bflo(pC[jj]) * a0 + bfhi(pC[jj]) * a1;
          acc3 += bflo(pD[jj]) * a0 + bfhi(pD[jj]) * a1;
        }
      }
    } else {
      #pragma unroll
      for (int q = 0; q < 13; ++q) {
        uint4 wA = w4[q];
        const uint_t* pA = (const uint_t*)&wA;
        #pragma unroll
        for (int jj = 0; jj < 4; ++jj) {
          uint_t ua = s_tile[(q * 4 + jj) * 64 + lane];
          acc0 += bflo(pA[jj]) * bflo(ua) + bfhi(pA[jj]) * bfhi(ua);
        }
      }
    }
    __syncthreads();
  }

  if (isGate) {
    float gi = acc0 + gbias[hglob];
    float gf = acc1 + gbias[512 + hglob];
    float gg = acc2 + gbias[1024 + hglob];
    float go = acc3 + gbias[1536 + hglob];
    float c0 = g_c[(size_t)hglob * 64 + lane];
    float cn = sigf(gf) * c0 + sigf(gi) * tanhf(gg);
    float hn = sigf(go) * tanhf(cn);
    g_c[(size_t)hglob * 64 + lane] = cn;
    s_h[u * 64 + lane] = hn;
    __syncthreads();
    if (tid < 256) {
      int q = tid >> 6;
      float h0 = s_h[(2 * q) * 64 + lane], h1 = s_h[(2 * q + 1) * 64 + lane];
      int kp = 160 + 256 * (par ^ 1) + blk * 4 + q;
      A2[(size_t)kp * 64 + lane] = packbf(h0, h1);
    }
  } else {
    int j = orow - 2048;
    out[((size_t)lane * TT + (t - 1)) * DD + j] = sigf(acc0 + out_b[j]);
  }
}

// ============ K2: head projections GEMM (weight-stationary; proven) ============
__global__ __launch_bounds__(512) void k2_heads(
    int wslot, const uint_t* __restrict__ W2h,
    const float* __restrict__ read_b, const float* __restrict__ write_b,
    const uint_t* __restrict__ A2, float* __restrict__ g_headp) {
  const int blk = blockIdx.x, tid = threadIdx.x;
  const int lane = tid & 63, u = tid >> 6;
  const int r = blk * 8 + u;
  __shared__ uint_t s_tile[64 * 64];
  __shared__ float s_tr[8 * 65];
  const int hbase = 160 + 256 * wslot;
  float acc = 0.f;
  const uint_t* wrow = W2h + (size_t)r * 256;
  for (int c = 0; c < 4; ++c) {
    for (int i = tid; i < 64 * 64; i += 512) {
      int kk = i >> 6, bb = i & 63;
      s_tile[i] = A2[(size_t)(hbase + c * 64 + kk) * 64 + bb];
    }
    __syncthreads();
    #pragma unroll 4
    for (int kk = 0; kk < 64; ++kk) {
      uint_t ua = s_tile[kk * 64 + lane];
      uint_t w = wrow[c * 64 + kk];
      acc += bflo(w) * bflo(ua) + bfhi(w) * bfhi(ua);
    }
    __syncthreads();
  }
  acc += (r < 280) ? read_b[r] : write_b[r - 280];
  s_tr[u * 65 + lane] = acc;
  __syncthreads();
  if (tid < 128) {
    int bb = tid & 63, half = tid >> 6;
    float4 v;
    v.x = s_tr[(half * 4 + 0) * 65 + bb];
    v.y = s_tr[(half * 4 + 1) * 65 + bb];
    v.z = s_tr[(half * 4 + 2) * 65 + bb];
    v.w = s_tr[(half * 4 + 3) * 65 + bb];
    *(float4*)(g_headp + (size_t)bb * 1088 + blk * 8 + half * 4) = v;
  }
}

// ============ K3: per-batch memory phase — LDS mem, 2 sweeps/head ============
// LDS layout: row*32 uints; 16B-unit rotation: global unit g stored at slot (g+row)&7.
__global__ __launch_bounds__(1024) void k3_mem(
    int t, const float* __restrict__ x, const float* __restrict__ g_headp,
    ushort_t* __restrict__ g_mem, uint_t* __restrict__ A2,
    float* __restrict__ g_ws) {
  const int b = blockIdx.x, tid = threadIdx.x;
  const int lane = tid & 63, wave = tid >> 6;
  extern __shared__ uint_t s_mem[];            // 131072 B
  __shared__ alignas(16) float s_proj[1088];   // all head projections (bias folded)
  __shared__ alignas(16) float s_eall[256];    // sigmoid(e), 4 heads
  __shared__ float s_kk[8];                    // key |k|^2 per slot
  __shared__ alignas(16) float s_wgA[1024];    // wgR, then wR final
  __shared__ alignas(16) float s_wgB[1024];    // wgW, then wW final
  __shared__ alignas(16) float s_part[1024];
  __shared__ alignas(16) float s_reads[RR * VV];
  __shared__ float s_redR[16];
  __shared__ float s_redW[16];
  uint_t* m32 = (uint_t*)(g_mem + (size_t)b * (NN * VV));
  const float* hp = g_headp + (size_t)b * 1088;

  // ---- prefetch ws history (8 slots) into registers (latency hidden) ----
  float wsr[8];
  #pragma unroll
  for (int s2 = 0; s2 < 8; ++s2) wsr[s2] = g_ws[(size_t)(b * 8 + s2) * 1024 + tid];

  // ---- stage all projections ----
  for (int i = tid; i < 1072; i += 1024) s_proj[i] = hp[i];
  __syncthreads();
  // e-sigmoids + key norms (visible after S1 of head 0)
  if (tid < 256) s_eall[tid] = sigf(s_proj[280 + (tid >> 6) * 198 + 70 + (tid & 63)]);
  if (wave < 8) {
    int base = (wave & 1) ? (280 + (wave >> 1) * 198) : ((wave >> 1) * 70);
    float v = s_proj[base + lane];
    v = v * v;
    #pragma unroll
    for (int o = 32; o; o >>= 1) v += __shfl_xor(v, o);
    if (lane == 0) s_kk[wave] = v;
  }

  // ---- initial global->LDS + head-0 dot/nrm (thread = row) ----
  float dotR = 0.f, dotW = 0.f, nrm2 = 0.f;
  {
    const uint4* rowp = (const uint4*)m32 + tid * 8;
    uint4* srow = (uint4*)(s_mem + tid * 32);
    const float2* krp = (const float2*)(s_proj);
    const float2* kwp = (const float2*)(s_proj + 280);
    #pragma unroll
    for (int g = 0; g < 8; ++g) {
      uint4 m = rowp[g];
      srow[(g + tid) & 7] = m;
      const uint_t* pm = (const uint_t*)&m;
      #pragma unroll
      for (int jj = 0; jj < 4; ++jj) {
        float v0 = bflo(pm[jj]), v1 = bfhi(pm[jj]);
        float2 kr = krp[g * 4 + jj];
        float2 kw = kwp[g * 4 + jj];
        nrm2 += v0 * v0 + v1 * v1;
        dotR += v0 * kr.x + v1 * kr.y;
        dotW += v0 * kw.x + v1 * kw.y;
      }
    }
  }

  #pragma unroll
  for (int hd = 0; hd < RR; ++hd) {
    const int kbR = hd * 70, kbW = 280 + hd * 198;

    // ---- dual softmax chain ----
    float na = fmaxf(sqrtf(nrm2), 1e-8f);
    float nbR = fmaxf(sqrtf(s_kk[2 * hd]), 1e-8f);
    float nbW = fmaxf(sqrtf(s_kk[2 * hd + 1]), 1e-8f);
    float betaR = splus(s_proj[kbR + 64]), betaW = splus(s_proj[kbW + 64]);
    float gR = sigf(s_proj[kbR + 65]), gW = sigf(s_proj[kbW + 65]);
    float r0 = s_proj[kbR + 66], r1 = s_proj[kbR + 67], r2 = s_proj[kbR + 68];
    float q0 = s_proj[kbW + 66], q1 = s_proj[kbW + 67], q2 = s_proj[kbW + 68];
    float mxR = fmaxf(r0, fmaxf(r1, r2)), mxW = fmaxf(q0, fmaxf(q1, q2));
    float eR0 = __expf(r0 - mxR), eR1 = __expf(r1 - mxR), eR2 = __expf(r2 - mxR);
    float eW0 = __expf(q0 - mxW), eW1 = __expf(q1 - mxW), eW2 = __expf(q2 - mxW);
    float siR = 1.0f / (eR0 + eR1 + eR2), siW = 1.0f / (eW0 + eW1 + eW2);
    float gamR = 1.0f + splus(s_proj[kbR + 69]), gamW = 1.0f + splus(s_proj[kbW + 69]);
    float eeR = __expf(betaR * dotR / (na * nbR));   // |z|<=beta: no max-sub
    float eeW = __expf(betaW * dotW / (na * nbW));
    float vR = eeR, vW = eeW;
    #pragma unroll
    for (int o = 32; o; o >>= 1) { vR += __shfl_xor(vR, o); vW += __shfl_xor(vW, o); }
    if (lane == 0) { s_redR[wave] = vR; s_redW[wave] = vW; }
    __syncthreads();                              // S1
    float SR = 0.f, SW = 0.f;
    #pragma unroll
    for (int w = 0; w < 16; ++w) { SR += s_redR[w]; SW += s_redW[w]; }
    float wgR = gR * (eeR / SR) + (1.0f - gR) * wsr[2 * hd];
    float wgW = gW * (eeW / SW) + (1.0f - gW) * wsr[2 * hd + 1];
    s_wgA[tid] = wgR;
    s_wgB[tid] = wgW;
    __syncthreads();                              // S2
    int tm = (tid + 1023) & 1023, tp = (tid + 1) & 1023;
    float wsnR = (eR0 * siR) * s_wgA[tm] + (eR1 * siR) * s_wgA[tid] + (eR2 * siR) * s_wgA[tp];
    float wsnW = (eW0 * siW) * s_wgB[tm] + (eW1 * siW) * s_wgB[tid] + (eW2 * siW) * s_wgB[tp];
    float wpR = __expf(gamR * __logf(wsnR));
    float wpW = __expf(gamW * __logf(wsnW));
    vR = wpR; vW = wpW;
    #pragma unroll
    for (int o = 32; o; o >>= 1) { vR += __shfl_xor(vR, o); vW += __shfl_xor(vW, o); }
    if (lane == 0) { s_redR[wave] = vR; s_redW[wave] = vW; }
    __syncthreads();                              // S3
    float ZR = 0.f, ZW = 0.f;
    #pragma unroll
    for (int w = 0; w < 16; ++w) { ZR += s_redR[w]; ZW += s_redW[w]; }
    float wRf = wpR / (ZR + 1e-16f);
    float wWf = wpW / (ZW + 1e-16f);
    wsr[2 * hd] = wRf;
    wsr[2 * hd + 1] = wWf;
    s_wgA[tid] = wRf;
    s_wgB[tid] = wWf;
    g_ws[(size_t)(b * 8 + 2 * hd) * 1024 + tid] = wRf;
    g_ws[(size_t)(b * 8 + 2 * hd + 1) * 1024 + tid] = wWf;
    __syncthreads();                              // S4: wR/wW visible

    if (hd < 3) {
      // ---- sweep1: einsum, column-major (pre-erase) ----
      {
        const int cp = lane & 31, half = lane >> 5;
        const int rbase = wave * 64 + half;
        float acc0 = 0.f, acc1 = 0.f;
        #pragma unroll 8
        for (int q = 0; q < 32; ++q) {
          int row = rbase + 2 * q;
          int addr = row * 32 + (((cp >> 2) + row) & 7) * 4 + (cp & 3);
          uint_t uu = s_mem[addr];
          float wRn = s_wgA[row];
          acc0 += wRn * bflo(uu);
          acc1 += wRn * bfhi(uu);
        }
        acc0 += __shfl_xor(acc0, 32);
        acc1 += __shfl_xor(acc1, 32);
        if (half == 0) *(float2*)(s_part + wave * 64 + 2 * cp) = make_float2(acc0, acc1);
      }
      __syncthreads();                            // S5: einsum reads done
      // ---- sweep2: erase row-major in LDS + next head's dot/nrm (fused) ----
      {
        const int row = tid;
        uint4* srow = (uint4*)(s_mem + row * 32);
        const float2* ep = (const float2*)(s_eall + hd * 64);
        const float2* ap = (const float2*)(s_proj + kbW + 134);
        const float2* krn = (const float2*)(s_proj + (hd + 1) * 70);
        const float2* kwn = (const float2*)(s_proj + 280 + (hd + 1) * 198);
        float dR = 0.f, dW = 0.f, nn = 0.f;
        #pragma unroll
        for (int g = 0; g < 8; ++g) {
          uint4 m = srow[(g + row) & 7];
          const uint_t* pm = (const uint_t*)&m;
          uint4 nu;
          uint_t* pn = (uint_t*)&nu;
          #pragma unroll
          for (int jj = 0; jj < 4; ++jj) {
            float v0 = bflo(pm[jj]), v1 = bfhi(pm[jj]);
            float2 ev = ep[g * 4 + jj];
            float2 av = ap[g * 4 + jj];
            float n0 = v0 * (1.f - wWf * ev.x) + wWf * av.x;
            float n1 = v1 * (1.f - wWf * ev.y) + wWf * av.y;
            pn[jj] = packbf(n0, n1);
            float2 kr = krn[g * 4 + jj];
            float2 kw = kwn[g * 4 + jj];
            dR += n0 * kr.x + n1 * kr.y;
            dW += n0 * kw.x + n1 * kw.y;
            nn += n0 * n0 + n1 * n1;
          }
          srow[(g + row) & 7] = nu;
        }
        dotR = dR; dotW = dW; nrm2 = nn;
      }
    } else {
      // ---- hd=3: fused einsum + erase, column-major; final mem -> global ----
      const int cp = lane & 31, half = lane >> 5;
      const float e0 = s_eall[192 + 2 * cp], e1 = s_eall[192 + 2 * cp + 1];
      const float a0 = s_proj[kbW + 134 + 2 * cp], a1 = s_proj[kbW + 134 + 2 * cp + 1];
      const int rbase = wave * 64 + half;
      float acc0 = 0.f, acc1 = 0.f;
      #pragma unroll 8
      for (int q = 0; q < 32; ++q) {
        int row = rbase + 2 * q;
        int addr = row * 32 + (((cp >> 2) + row) & 7) * 4 + (cp & 3);
        uint_t uu = s_mem[addr];
        float wRn = s_wgA[row];
        float wWn = s_wgB[row];
        float v0 = bflo(uu), v1 = bfhi(uu);
        acc0 += wRn * v0;
        acc1 += wRn * v1;
        float n0 = v0 * (1.f - wWn * e0) + wWn * a0;
        float n1 = v1 * (1.f - wWn * e1) + wWn * a1;
        m32[(size_t)row * 32 + cp] = packbf(n0, n1);   // plain store: L2 write-combine
      }
      acc0 += __shfl_xor(acc0, 32);
      acc1 += __shfl_xor(acc1, 32);
      if (half == 0) *(float2*)(s_part + wave * 64 + 2 * cp) = make_float2(acc0, acc1);
      __syncthreads();                            // S5
    }
    // combine einsum partials -> s_reads (s_part stable since S5)
    if (tid < VV) {
      float s = 0.f;
      #pragma unroll
      for (int w2 = 0; w2 < 16; ++w2) s += s_part[w2 * 64 + tid];
      s_reads[hd * VV + tid] = s;
    }
  } // hd
  __syncthreads();

  // ---- publish reads_t and x_{t+1} into A2 (bf16 pairs) ----
  if (tid < 128)
    A2[(size_t)(32 + tid) * 64 + b] = packbf(s_reads[2 * tid], s_reads[2 * tid + 1]);
  if (tid < 32 && t + 1 < TT) {
    float v0 = x[((size_t)b * TT + t + 1) * DD + 2 * tid];
    float v1 = x[((size_t)b * TT + t + 1) * DD + 2 * tid + 1];
    A2[(size_t)tid * 64 + b] = packbf(v0, v1);
  }
}

extern "C" void kernel_launch(void* const* d_in, const int* in_sizes, int n_in,
                              void* d_out, int out_size, void* d_ws, size_t ws_size,
                              hipStream_t stream) {
  char* ws = (char*)d_ws;
  ushort_t* g_mem = (ushort_t*)ws;                 //  8,388,608
  uint_t* g_A2    = (uint_t*)(ws + 8388608);       //    172,032
  float* g_c      = (float*)(ws + 8560640);        //    131,072
  float* g_ws     = (float*)(ws + 8691712);        //  2,097,152
  float* g_headp  = (float*)(ws + 10788864);       //    278,528
  uint_t* W2g     = (uint_t*)(ws + 11067392);      //  3,514,368
  uint_t* W2h     = (uint_t*)(ws + 14581760);      //  1,097,728
  float* gbias    = (float*)(ws + 15679488);       //      8,192  (~15.7 MB)

  const float* x        = (const float*)d_in[0];
  const float* mem_bias = (const float*)d_in[1];
  const float* h_bias   = (const float*)d_in[2];
  const float* c_bias   = (const float*)d_in[3];
  const float* W_ih     = (const float*)d_in[4];
  const float* W_hh     = (const float*)d_in[5];
  const float* b_ih     = (const float*)d_in[6];
  const float* b_hh     = (const float*)d_in[7];
  const float* read_W   = (const float*)d_in[8];
  const float* read_b   = (const float*)d_in[9];
  const float* write_W  = (const float*)d_in[10];
  const float* write_b  = (const float*)d_in[11];
  const float* read_init= (const float*)d_in[12];
  const float* out_W    = (const float*)d_in[13];
  const float* out_b    = (const float*)d_in[14];
  float* out = (float*)d_out;

  bias_kernel<<<8, 256, 0, stream>>>(b_ih, b_hh, gbias);
  build_gw<<<3432, 256, 0, stream>>>(W_ih, W_hh, out_W, W2g);
  build_hw<<<1072, 256, 0, stream>>>(read_W, write_W, W2h);
  k0_init<<<64, 1024, 0, stream>>>(x, mem_bias, h_bias, c_bias, read_init,
                                   g_mem, g_A2, g_c, g_ws);
  for (int t = 0; t < TT; ++t) {
    k1_gates<<<72, 512, 0, stream>>>(t, 64, t & 1, W2g, gbias, g_A2, g_c, out_b, out);
    k2_heads<<<134, 512, 0, stream>>>((t + 1) & 1, W2h, read_b, write_b, g_A2, g_headp);
    k3_mem<<<64, 1024, 131072, stream>>>(t, x, g_headp, g_mem, g_A2, g_ws);
  }
  // final out row batch: out(t=31) from h_31 (slot 0) + reads_31
  k1_gates<<<8, 512, 0, stream>>>(TT, 0, 0, W2g, gbias, g_A2, g_c, out_b, out);
}

// Round 15
// 4639.661 us; speedup vs baseline: 1.4514x; 1.4069x over previous
//
#include <hip/hip_runtime.h>
#include <math.h>

#define TT 32
#define DD 64
#define NN 1024
#define VV 64
#define RR 4
#define HH 512

typedef unsigned int uint_t;
typedef unsigned short ushort_t;

__device__ __forceinline__ float sigf(float x) { return 1.0f / (1.0f + __expf(-x)); }
__device__ __forceinline__ float splus(float x) {
  return (x > 0.f) ? (x + log1pf(__expf(-x))) : log1pf(__expf(x));
}
__device__ __forceinline__ ushort_t bfr(float f) {
  uint_t u = __float_as_uint(f);
  return (ushort_t)((u + 0x7fffu + ((u >> 16) & 1u)) >> 16);
}
__device__ __forceinline__ float bflo(uint_t u) { return __uint_as_float(u << 16); }
__device__ __forceinline__ float bfhi(uint_t u) { return __uint_as_float(u & 0xffff0000u); }
__device__ __forceinline__ uint_t packbf(float a, float b) {
  return (uint_t)bfr(a) | ((uint_t)bfr(b) << 16);
}

// ============ pre-kernels (every launch; deterministic) ============
__global__ void build_gw(const float* __restrict__ W_ih, const float* __restrict__ W_hh,
                         const float* __restrict__ out_W, uint_t* __restrict__ W2g) {
  int idx = blockIdx.x * 256 + threadIdx.x;           // 2112*416
  if (idx >= 2112 * 416) return;
  int r = idx / 416, kp = idx - r * 416;
  float v[2];
  #pragma unroll
  for (int q = 0; q < 2; ++q) {
    int k = 2 * kp + q;
    float f;
    if (r < 2048) {
      int h = r >> 2, g = r & 3, row = g * 512 + h;
      f = (k < 320) ? W_ih[(size_t)row * 320 + k] : W_hh[(size_t)row * 512 + (k - 320)];
    } else {
      int j = r - 2048;
      if (k < 64) f = 0.f;
      else if (k < 320) f = out_W[(size_t)j * 768 + 512 + (k - 64)];
      else f = out_W[(size_t)j * 768 + (k - 320)];
    }
    v[q] = f;
  }
  W2g[idx] = packbf(v[0], v[1]);
}
__global__ void build_hw(const float* __restrict__ read_W, const float* __restrict__ write_W,
                         uint_t* __restrict__ W2h) {
  int idx = blockIdx.x * 256 + threadIdx.x;           // 1072*256
  if (idx >= 1072 * 256) return;
  int r = idx >> 8, kp = idx & 255;
  const float* src = (r < 280) ? (read_W + (size_t)r * 512) : (write_W + (size_t)(r - 280) * 512);
  W2h[idx] = packbf(src[2 * kp], src[2 * kp + 1]);
}
__global__ void bias_kernel(const float* __restrict__ bi, const float* __restrict__ bh,
                            float* __restrict__ o) {
  int i = blockIdx.x * 256 + threadIdx.x;
  if (i < 2048) o[i] = bi[i] + bh[i];
}
__global__ void k0_init(const float* __restrict__ x, const float* __restrict__ mem_bias,
                        const float* __restrict__ h_bias, const float* __restrict__ c_bias,
                        const float* __restrict__ read_init,
                        ushort_t* __restrict__ g_mem, uint_t* __restrict__ A2,
                        float* __restrict__ g_c, float* __restrict__ g_ws) {
  const int b = blockIdx.x, tid = threadIdx.x;
  {
    const float4* src = (const float4*)(mem_bias + (size_t)tid * VV);
    uint4* dst = (uint4*)(g_mem + (size_t)b * (NN * VV) + (size_t)tid * VV);
    #pragma unroll
    for (int p = 0; p < 8; ++p) {
      float4 va = src[2 * p], vb = src[2 * p + 1];
      uint4 o;
      o.x = packbf(va.x, va.y); o.y = packbf(va.z, va.w);
      o.z = packbf(vb.x, vb.y); o.w = packbf(vb.z, vb.w);
      dst[p] = o;
    }
  }
  if (tid < 416) {
    float v0, v1;
    if (tid < 32)      { v0 = x[((size_t)b * TT) * DD + 2 * tid]; v1 = x[((size_t)b * TT) * DD + 2 * tid + 1]; }
    else if (tid < 160){ int e = 2 * (tid - 32); v0 = read_init[e]; v1 = read_init[e + 1]; }
    else               { int e = 2 * (tid - 160); v0 = h_bias[e]; v1 = h_bias[e + 1]; }
    A2[(size_t)tid * 64 + b] = packbf(v0, v1);
  }
  if (tid < 512) g_c[(size_t)tid * 64 + b] = c_bias[tid];
  for (int i = tid; i < 8192; i += 1024) g_ws[(size_t)b * 8192 + i] = 0.f;
}

// ============ K1: gates GEMM + LSTM + out(t-1) rows (uint4 weight loads) ============
__global__ __launch_bounds__(512) void k1_gates(
    int t, int nGate, int par,
    const uint_t* __restrict__ W2g, const float* __restrict__ gbias,
    uint_t* __restrict__ A2, float* __restrict__ g_c,
    const float* __restrict__ out_b, float* __restrict__ out) {
  const int blk = blockIdx.x, tid = threadIdx.x;
  const int lane = tid & 63, u = tid >> 6;
  const bool isGate = (blk < nGate);
  if (!isGate && t == 0) return;
  __shared__ uint_t s_tile[52 * 64];
  __shared__ float s_h[8 * 64];
  float acc0 = 0.f, acc1 = 0.f, acc2 = 0.f, acc3 = 0.f;
  const int hglob = blk * 8 + u;
  const int orow = 2048 + (blk - nGate) * 8 + u;
  const size_t wbase = isGate ? (size_t)(hglob * 4) * 416 : (size_t)orow * 416;

  for (int c = 0; c < 8; ++c) {
    for (int i = tid; i < 52 * 64; i += 512) {
      int kk = i >> 6, bb = i & 63;
      int kpg = c * 52 + kk;
      int phys = (kpg < 160) ? kpg : kpg + 256 * par;
      s_tile[i] = A2[(size_t)phys * 64 + bb];
    }
    __syncthreads();
    const uint4* w4 = (const uint4*)(W2g + wbase) + c * 13;
    if (isGate) {
      #pragma unroll
      for (int q = 0; q < 13; ++q) {
        uint4 wA = w4[q], wB = w4[104 + q], wC = w4[208 + q], wD = w4[312 + q];
        const uint_t* pA = (const uint_t*)&wA;
        const uint_t* pB = (const uint_t*)&wB;
        const uint_t* pC = (const uint_t*)&wC;
        const uint_t* pD = (const uint_t*)&wD;
        #pragma unroll
        for (int jj = 0; jj < 4; ++jj) {
          uint_t ua = s_tile[(q * 4 + jj) * 64 + lane];
          float a0 = bflo(ua), a1 = bfhi(ua);
          acc0 += bflo(pA[jj]) * a0 + bfhi(pA[jj]) * a1;
          acc1 += bflo(pB[jj]) * a0 + bfhi(pB[jj]) * a1;
          acc2 += bflo(pC[jj]) * a0 + bfhi(pC[jj]) * a1;
          acc3 += bflo(pD[jj]) * a0 + bfhi(pD[jj]) * a1;
        }
      }
    } else {
      #pragma unroll
      for (int q = 0; q < 13; ++q) {
        uint4 wA = w4[q];
        const uint_t* pA = (const uint_t*)&wA;
        #pragma unroll
        for (int jj = 0; jj < 4; ++jj) {
          uint_t ua = s_tile[(q * 4 + jj) * 64 + lane];
          acc0 += bflo(pA[jj]) * bflo(ua) + bfhi(pA[jj]) * bfhi(ua);
        }
      }
    }
    __syncthreads();
  }

  if (isGate) {
    float gi = acc0 + gbias[hglob];
    float gf = acc1 + gbias[512 + hglob];
    float gg = acc2 + gbias[1024 + hglob];
    float go = acc3 + gbias[1536 + hglob];
    float c0 = g_c[(size_t)hglob * 64 + lane];
    float cn = sigf(gf) * c0 + sigf(gi) * tanhf(gg);
    float hn = sigf(go) * tanhf(cn);
    g_c[(size_t)hglob * 64 + lane] = cn;
    s_h[u * 64 + lane] = hn;
    __syncthreads();
    if (tid < 256) {
      int q = tid >> 6;
      float h0 = s_h[(2 * q) * 64 + lane], h1 = s_h[(2 * q + 1) * 64 + lane];
      int kp = 160 + 256 * (par ^ 1) + blk * 4 + q;
      A2[(size_t)kp * 64 + lane] = packbf(h0, h1);
    }
  } else {
    int j = orow - 2048;
    out[((size_t)lane * TT + (t - 1)) * DD + j] = sigf(acc0 + out_b[j]);
  }
}

// ============ K2: head projections GEMM (weight-stationary; proven R10) ============
__global__ __launch_bounds__(512) void k2_heads(
    int wslot, const uint_t* __restrict__ W2h,
    const float* __restrict__ read_b, const float* __restrict__ write_b,
    const uint_t* __restrict__ A2, float* __restrict__ g_headp) {
  const int blk = blockIdx.x, tid = threadIdx.x;
  const int lane = tid & 63, u = tid >> 6;
  const int r = blk * 8 + u;
  __shared__ uint_t s_tile[64 * 64];
  __shared__ float s_tr[8 * 65];
  const int hbase = 160 + 256 * wslot;
  float acc = 0.f;
  const uint_t* wrow = W2h + (size_t)r * 256;
  for (int c = 0; c < 4; ++c) {
    for (int i = tid; i < 64 * 64; i += 512) {
      int kk = i >> 6, bb = i & 63;
      s_tile[i] = A2[(size_t)(hbase + c * 64 + kk) * 64 + bb];
    }
    __syncthreads();
    #pragma unroll 4
    for (int kk = 0; kk < 64; ++kk) {
      uint_t ua = s_tile[kk * 64 + lane];
      uint_t w = wrow[c * 64 + kk];
      acc += bflo(w) * bflo(ua) + bfhi(w) * bfhi(ua);
    }
    __syncthreads();
  }
  acc += (r < 280) ? read_b[r] : write_b[r - 280];
  s_tr[u * 65 + lane] = acc;
  __syncthreads();
  if (tid < 128) {
    int bb = tid & 63, half = tid >> 6;
    float4 v;
    v.x = s_tr[(half * 4 + 0) * 65 + bb];
    v.y = s_tr[(half * 4 + 1) * 65 + bb];
    v.z = s_tr[(half * 4 + 2) * 65 + bb];
    v.w = s_tr[(half * 4 + 3) * 65 + bb];
    *(float4*)(g_headp + (size_t)bb * 1088 + blk * 8 + half * 4) = v;
  }
}

// ============ K3: per-batch memory phase — mem LDS-resident (proven R10) ============
// Dynamic LDS: 1024 rows x 32 uints, rotation-swizzled: slot(row,c) = (c+row)&31.
__global__ __launch_bounds__(1024) void k3_mem(
    int t, const float* __restrict__ x, const float* __restrict__ g_headp,
    ushort_t* __restrict__ g_mem, uint_t* __restrict__ A2,
    float* __restrict__ g_ws) {
  const int b = blockIdx.x, tid = threadIdx.x;
  const int lane = tid & 63, wave = tid >> 6;
  extern __shared__ uint_t s_mem[];            // 131072 B
  __shared__ alignas(16) float s_wgA[1024];    // wgR, then wR final
  __shared__ alignas(16) float s_wgB[1024];    // wgW, then wW final
  __shared__ alignas(16) float s_part[1024];
  __shared__ alignas(16) float s_reads[RR * VV];
  __shared__ alignas(16) float s_or[72];
  __shared__ alignas(16) float s_ow[200];
  __shared__ alignas(16) float s_e[VV];
  __shared__ alignas(16) float s_a[VV];
  __shared__ float s_redR[16];
  __shared__ float s_redW[16];
  uint_t* m32 = (uint_t*)(g_mem + (size_t)b * (NN * VV));
  const float* hp = g_headp + (size_t)b * 1088;

  for (int hd = 0; hd < RR; ++hd) {
    if (tid < 70) s_or[tid] = hp[hd * 70 + tid];
    else if (tid >= 128 && tid < 326) s_ow[tid - 128] = hp[280 + hd * 198 + (tid - 128)];
    __syncthreads();                              // S0
    if (tid < VV) { s_e[tid] = sigf(s_ow[70 + tid]); s_a[tid] = s_ow[134 + tid]; }

    float wprevR = g_ws[(size_t)(b * 8 + 2 * hd) * 1024 + tid];
    float wprevW = g_ws[(size_t)(b * 8 + 2 * hd + 1) * 1024 + tid];

    // ---- dot pass over own row (tid): dual keys + |row|^2 ----
    float dotR = 0.f, dotW = 0.f, kkR = 0.f, kkW = 0.f, nrm2 = 0.f;
    if (hd == 0) {
      // stream from EA (coalesced uint4) + deposit rotated into LDS
      const uint4* rowp = (const uint4*)(m32 + (size_t)tid * 32);
      const float4* orf = (const float4*)s_or;
      const float4* owf = (const float4*)s_ow;
      #pragma unroll
      for (int p = 0; p < 8; ++p) {
        uint4 m = rowp[p];
        s_mem[tid * 32 + ((4 * p + 0 + tid) & 31)] = m.x;
        s_mem[tid * 32 + ((4 * p + 1 + tid) & 31)] = m.y;
        s_mem[tid * 32 + ((4 * p + 2 + tid) & 31)] = m.z;
        s_mem[tid * 32 + ((4 * p + 3 + tid) & 31)] = m.w;
        float4 ka = orf[2 * p], kb = orf[2 * p + 1];
        float4 wa = owf[2 * p], wb = owf[2 * p + 1];
        kkR += ka.x * ka.x + ka.y * ka.y + ka.z * ka.z + ka.w * ka.w +
               kb.x * kb.x + kb.y * kb.y + kb.z * kb.z + kb.w * kb.w;
        kkW += wa.x * wa.x + wa.y * wa.y + wa.z * wa.z + wa.w * wa.w +
               wb.x * wb.x + wb.y * wb.y + wb.z * wb.z + wb.w * wb.w;
        float m0 = bflo(m.x), m1 = bfhi(m.x), m2 = bflo(m.y), m3 = bfhi(m.y);
        float m4 = bflo(m.z), m5 = bfhi(m.z), m6 = bflo(m.w), m7 = bfhi(m.w);
        nrm2 += m0 * m0 + m1 * m1 + m2 * m2 + m3 * m3 + m4 * m4 + m5 * m5 + m6 * m6 + m7 * m7;
        dotR += m0 * ka.x + m1 * ka.y + m2 * ka.z + m3 * ka.w +
                m4 * kb.x + m5 * kb.y + m6 * kb.z + m7 * kb.w;
        dotW += m0 * wa.x + m1 * wa.y + m2 * wa.z + m3 * wa.w +
                m4 * wb.x + m5 * wb.y + m6 * wb.z + m7 * wb.w;
      }
    } else {
      #pragma unroll 8
      for (int c = 0; c < 32; ++c) {
        uint_t u = s_mem[tid * 32 + ((c + tid) & 31)];
        float v0 = bflo(u), v1 = bfhi(u);
        float kR0 = s_or[2 * c], kR1 = s_or[2 * c + 1];
        float kW0 = s_ow[2 * c], kW1 = s_ow[2 * c + 1];
        nrm2 += v0 * v0 + v1 * v1;
        dotR += v0 * kR0 + v1 * kR1;
        dotW += v0 * kW0 + v1 * kW1;
        kkR += kR0 * kR0 + kR1 * kR1;
        kkW += kW0 * kW0 + kW1 * kW1;
      }
    }
    float na = fmaxf(sqrtf(nrm2), 1e-8f);

    // ---- dual softmax chain ----
    float nbR = fmaxf(sqrtf(kkR), 1e-8f), nbW = fmaxf(sqrtf(kkW), 1e-8f);
    float betaR = splus(s_or[64]), betaW = splus(s_ow[64]);
    float gR = sigf(s_or[65]), gW = sigf(s_ow[65]);
    float r0 = s_or[66], r1 = s_or[67], r2 = s_or[68];
    float q0 = s_ow[66], q1 = s_ow[67], q2 = s_ow[68];
    float mxR = fmaxf(r0, fmaxf(r1, r2)), mxW = fmaxf(q0, fmaxf(q1, q2));
    float eR0 = __expf(r0 - mxR), eR1 = __expf(r1 - mxR), eR2 = __expf(r2 - mxR);
    float eW0 = __expf(q0 - mxW), eW1 = __expf(q1 - mxW), eW2 = __expf(q2 - mxW);
    float siR = 1.0f / (eR0 + eR1 + eR2), siW = 1.0f / (eW0 + eW1 + eW2);
    float gamR = 1.0f + splus(s_or[69]), gamW = 1.0f + splus(s_ow[69]);
    float eeR = __expf(betaR * dotR / (na * nbR));   // |z|<=beta: no max-sub
    float eeW = __expf(betaW * dotW / (na * nbW));
    float vR = eeR, vW = eeW;
    #pragma unroll
    for (int o = 32; o; o >>= 1) { vR += __shfl_xor(vR, o); vW += __shfl_xor(vW, o); }
    if (lane == 0) { s_redR[wave] = vR; s_redW[wave] = vW; }
    __syncthreads();                              // S1
    float SR = 0.f, SW = 0.f;
    #pragma unroll
    for (int w = 0; w < 16; ++w) { SR += s_redR[w]; SW += s_redW[w]; }
    float wgR = gR * (eeR / SR) + (1.0f - gR) * wprevR;
    float wgW = gW * (eeW / SW) + (1.0f - gW) * wprevW;
    s_wgA[tid] = wgR;
    s_wgB[tid] = wgW;
    __syncthreads();                              // S2
    int tm = (tid + 1023) & 1023, tp = (tid + 1) & 1023;
    float wsnR = (eR0 * siR) * s_wgA[tm] + (eR1 * siR) * s_wgA[tid] + (eR2 * siR) * s_wgA[tp];
    float wsnW = (eW0 * siW) * s_wgB[tm] + (eW1 * siW) * s_wgB[tid] + (eW2 * siW) * s_wgB[tp];
    float wpR = __expf(gamR * __logf(wsnR));
    float wpW = __expf(gamW * __logf(wsnW));
    vR = wpR; vW = wpW;
    #pragma unroll
    for (int o = 32; o; o >>= 1) { vR += __shfl_xor(vR, o); vW += __shfl_xor(vW, o); }
    if (lane == 0) { s_redR[wave] = vR; s_redW[wave] = vW; }
    __syncthreads();                              // S3 (all shift reads done)
    float ZR = 0.f, ZW = 0.f;
    #pragma unroll
    for (int w = 0; w < 16; ++w) { ZR += s_redR[w]; ZW += s_redW[w]; }
    float wRf = wpR / (ZR + 1e-16f);
    float wWf = wpW / (ZW + 1e-16f);
    s_wgA[tid] = wRf;
    s_wgB[tid] = wWf;
    g_ws[(size_t)(b * 8 + 2 * hd) * 1024 + tid] = wRf;
    g_ws[(size_t)(b * 8 + 2 * hd + 1) * 1024 + tid] = wWf;
    __syncthreads();                              // S4: wR/wW visible

    // ---- fused einsum + erase in LDS (head 3 erase -> EA) ----
    {
      const int cp = lane & 31, half = lane >> 5;
      const float e0 = s_e[2 * cp], e1 = s_e[2 * cp + 1];
      const float a0 = s_a[2 * cp], a1 = s_a[2 * cp + 1];
      const int rbase = wave * 64 + half;
      float acc0 = 0.f, acc1 = 0.f;
      #pragma unroll 8
      for (int q = 0; q < 32; ++q) {
        int row = rbase + 2 * q;
        int addr = row * 32 + ((cp + row) & 31);
        uint_t uu = s_mem[addr];
        float wRn = s_wgA[row];
        float wWn = s_wgB[row];
        float v0 = bflo(uu), v1 = bfhi(uu);
        acc0 += wRn * v0; acc1 += wRn * v1;
        float n0 = v0 * (1.f - wWn * e0) + wWn * a0;
        float n1 = v1 * (1.f - wWn * e1) + wWn * a1;
        uint_t nu = packbf(n0, n1);
        if (hd < 3) s_mem[addr] = nu;
        else        m32[(size_t)row * 32 + cp] = nu;   // final mem -> EA, coalesced
      }
      acc0 += __shfl_xor(acc0, 32);
      acc1 += __shfl_xor(acc1, 32);
      if (half == 0) *(float2*)(s_part + wave * 64 + 2 * cp) = make_float2(acc0, acc1);
    }
    __syncthreads();                              // S5
    if (tid < VV) {
      float s = 0.f;
      #pragma unroll
      for (int w2 = 0; w2 < 16; ++w2) s += s_part[w2 * 64 + tid];
      s_reads[hd * VV + tid] = s;
    }
  } // hd
  __syncthreads();

  // publish reads_t and x_{t+1} into A (bf16 pairs)
  if (tid < 128)
    A2[(size_t)(32 + tid) * 64 + b] = packbf(s_reads[2 * tid], s_reads[2 * tid + 1]);
  if (tid < 32 && t + 1 < TT) {
    float v0 = x[((size_t)b * TT + t + 1) * DD + 2 * tid];
    float v1 = x[((size_t)b * TT + t + 1) * DD + 2 * tid + 1];
    A2[(size_t)tid * 64 + b] = packbf(v0, v1);
  }
}

extern "C" void kernel_launch(void* const* d_in, const int* in_sizes, int n_in,
                              void* d_out, int out_size, void* d_ws, size_t ws_size,
                              hipStream_t stream) {
  char* ws = (char*)d_ws;
  ushort_t* g_mem = (ushort_t*)ws;                 //  8,388,608
  uint_t* g_A2    = (uint_t*)(ws + 8388608);       //    172,032
  float* g_c      = (float*)(ws + 8560640);        //    131,072
  float* g_ws     = (float*)(ws + 8691712);        //  2,097,152
  float* g_headp  = (float*)(ws + 10788864);       //    278,528
  uint_t* W2g     = (uint_t*)(ws + 11067392);      //  3,514,368
  uint_t* W2h     = (uint_t*)(ws + 14581760);      //  1,097,728
  float* gbias    = (float*)(ws + 15679488);       //      8,192  (~15.7 MB)

  const float* x        = (const float*)d_in[0];
  const float* mem_bias = (const float*)d_in[1];
  const float* h_bias   = (const float*)d_in[2];
  const float* c_bias   = (const float*)d_in[3];
  const float* W_ih     = (const float*)d_in[4];
  const float* W_hh     = (const float*)d_in[5];
  const float* b_ih     = (const float*)d_in[6];
  const float* b_hh     = (const float*)d_in[7];
  const float* read_W   = (const float*)d_in[8];
  const float* read_b   = (const float*)d_in[9];
  const float* write_W  = (const float*)d_in[10];
  const float* write_b  = (const float*)d_in[11];
  const float* read_init= (const float*)d_in[12];
  const float* out_W    = (const float*)d_in[13];
  const float* out_b    = (const float*)d_in[14];
  float* out = (float*)d_out;

  bias_kernel<<<8, 256, 0, stream>>>(b_ih, b_hh, gbias);
  build_gw<<<3432, 256, 0, stream>>>(W_ih, W_hh, out_W, W2g);
  build_hw<<<1072, 256, 0, stream>>>(read_W, write_W, W2h);
  k0_init<<<64, 1024, 0, stream>>>(x, mem_bias, h_bias, c_bias, read_init,
                                   g_mem, g_A2, g_c, g_ws);
  for (int t = 0; t < TT; ++t) {
    k1_gates<<<72, 512, 0, stream>>>(t, 64, t & 1, W2g, gbias, g_A2, g_c, out_b, out);
    k2_heads<<<134, 512, 0, stream>>>((t + 1) & 1, W2h, read_b, write_b, g_A2, g_headp);
    k3_mem<<<64, 1024, 131072, stream>>>(t, x, g_headp, g_mem, g_A2, g_ws);
  }
  // final out row batch: out(t=31) from h_31 (slot 0) + reads_31
  k1_gates<<<8, 512, 0, stream>>>(TT, 0, 0, W2g, gbias, g_A2, g_c, out_b, out);
}

// Round 16
// 4326.079 us; speedup vs baseline: 1.5566x; 1.0725x over previous
//
#include <hip/hip_runtime.h>
#include <math.h>

#define TT 32
#define DD 64
#define NN 1024
#define VV 64
#define RR 4
#define HH 512

typedef unsigned int uint_t;
typedef unsigned short ushort_t;

__device__ __forceinline__ float sigf(float x) { return 1.0f / (1.0f + __expf(-x)); }
__device__ __forceinline__ float splus(float x) {
  return (x > 0.f) ? (x + log1pf(__expf(-x))) : log1pf(__expf(x));
}
__device__ __forceinline__ ushort_t bfr(float f) {
  uint_t u = __float_as_uint(f);
  return (ushort_t)((u + 0x7fffu + ((u >> 16) & 1u)) >> 16);
}
__device__ __forceinline__ float bflo(uint_t u) { return __uint_as_float(u << 16); }
__device__ __forceinline__ float bfhi(uint_t u) { return __uint_as_float(u & 0xffff0000u); }
__device__ __forceinline__ uint_t packbf(float a, float b) {
  return (uint_t)bfr(a) | ((uint_t)bfr(b) << 16);
}

// ============ pre-kernels (every launch; deterministic) ============
__global__ void build_gw(const float* __restrict__ W_ih, const float* __restrict__ W_hh,
                         const float* __restrict__ out_W, uint_t* __restrict__ W2g) {
  int idx = blockIdx.x * 256 + threadIdx.x;           // 2112*416
  if (idx >= 2112 * 416) return;
  int r = idx / 416, kp = idx - r * 416;
  float v[2];
  #pragma unroll
  for (int q = 0; q < 2; ++q) {
    int k = 2 * kp + q;
    float f;
    if (r < 2048) {
      int h = r >> 2, g = r & 3, row = g * 512 + h;
      f = (k < 320) ? W_ih[(size_t)row * 320 + k] : W_hh[(size_t)row * 512 + (k - 320)];
    } else {
      int j = r - 2048;
      if (k < 64) f = 0.f;
      else if (k < 320) f = out_W[(size_t)j * 768 + 512 + (k - 64)];
      else f = out_W[(size_t)j * 768 + (k - 320)];
    }
    v[q] = f;
  }
  W2g[idx] = packbf(v[0], v[1]);
}
__global__ void build_hw(const float* __restrict__ read_W, const float* __restrict__ write_W,
                         uint_t* __restrict__ W2h) {
  int idx = blockIdx.x * 256 + threadIdx.x;           // 1072*256
  if (idx >= 1072 * 256) return;
  int r = idx >> 8, kp = idx & 255;
  const float* src = (r < 280) ? (read_W + (size_t)r * 512) : (write_W + (size_t)(r - 280) * 512);
  W2h[idx] = packbf(src[2 * kp], src[2 * kp + 1]);
}
__global__ void bias_kernel(const float* __restrict__ bi, const float* __restrict__ bh,
                            float* __restrict__ o) {
  int i = blockIdx.x * 256 + threadIdx.x;
  if (i < 2048) o[i] = bi[i] + bh[i];
}
__global__ void k0_init(const float* __restrict__ x, const float* __restrict__ mem_bias,
                        const float* __restrict__ h_bias, const float* __restrict__ c_bias,
                        const float* __restrict__ read_init,
                        ushort_t* __restrict__ g_mem, uint_t* __restrict__ A2,
                        float* __restrict__ g_c, float* __restrict__ g_ws) {
  const int b = blockIdx.x, tid = threadIdx.x;
  {
    const float4* src = (const float4*)(mem_bias + (size_t)tid * VV);
    uint4* dst = (uint4*)(g_mem + (size_t)b * (NN * VV) + (size_t)tid * VV);
    #pragma unroll
    for (int p = 0; p < 8; ++p) {
      float4 va = src[2 * p], vb = src[2 * p + 1];
      uint4 o;
      o.x = packbf(va.x, va.y); o.y = packbf(va.z, va.w);
      o.z = packbf(vb.x, vb.y); o.w = packbf(vb.z, vb.w);
      dst[p] = o;
    }
  }
  if (tid < 416) {
    float v0, v1;
    if (tid < 32)      { v0 = x[((size_t)b * TT) * DD + 2 * tid]; v1 = x[((size_t)b * TT) * DD + 2 * tid + 1]; }
    else if (tid < 160){ int e = 2 * (tid - 32); v0 = read_init[e]; v1 = read_init[e + 1]; }
    else               { int e = 2 * (tid - 160); v0 = h_bias[e]; v1 = h_bias[e + 1]; }
    A2[(size_t)tid * 64 + b] = packbf(v0, v1);
  }
  if (tid < 512) g_c[(size_t)tid * 64 + b] = c_bias[tid];
  for (int i = tid; i < 8192; i += 1024) g_ws[(size_t)b * 8192 + i] = 0.f;
}

// ============ K1: gates GEMM + LSTM + out(t-1) rows (uint4 weight loads) ============
__global__ __launch_bounds__(512) void k1_gates(
    int t, int nGate, int par,
    const uint_t* __restrict__ W2g, const float* __restrict__ gbias,
    uint_t* __restrict__ A2, float* __restrict__ g_c,
    const float* __restrict__ out_b, float* __restrict__ out) {
  const int blk = blockIdx.x, tid = threadIdx.x;
  const int lane = tid & 63, u = tid >> 6;
  const bool isGate = (blk < nGate);
  if (!isGate && t == 0) return;
  __shared__ uint_t s_tile[52 * 64];
  __shared__ float s_h[8 * 64];
  float acc0 = 0.f, acc1 = 0.f, acc2 = 0.f, acc3 = 0.f;
  const int hglob = blk * 8 + u;
  const int orow = 2048 + (blk - nGate) * 8 + u;
  const size_t wbase = isGate ? (size_t)(hglob * 4) * 416 : (size_t)orow * 416;

  for (int c = 0; c < 8; ++c) {
    for (int i = tid; i < 52 * 64; i += 512) {
      int kk = i >> 6, bb = i & 63;
      int kpg = c * 52 + kk;
      int phys = (kpg < 160) ? kpg : kpg + 256 * par;
      s_tile[i] = A2[(size_t)phys * 64 + bb];
    }
    __syncthreads();
    const uint4* w4 = (const uint4*)(W2g + wbase) + c * 13;
    if (isGate) {
      #pragma unroll
      for (int q = 0; q < 13; ++q) {
        uint4 wA = w4[q], wB = w4[104 + q], wC = w4[208 + q], wD = w4[312 + q];
        const uint_t* pA = (const uint_t*)&wA;
        const uint_t* pB = (const uint_t*)&wB;
        const uint_t* pC = (const uint_t*)&wC;
        const uint_t* pD = (const uint_t*)&wD;
        #pragma unroll
        for (int jj = 0; jj < 4; ++jj) {
          uint_t ua = s_tile[(q * 4 + jj) * 64 + lane];
          float a0 = bflo(ua), a1 = bfhi(ua);
          acc0 += bflo(pA[jj]) * a0 + bfhi(pA[jj]) * a1;
          acc1 += bflo(pB[jj]) * a0 + bfhi(pB[jj]) * a1;
          acc2 += bflo(pC[jj]) * a0 + bfhi(pC[jj]) * a1;
          acc3 += bflo(pD[jj]) * a0 + bfhi(pD[jj]) * a1;
        }
      }
    } else {
      #pragma unroll
      for (int q = 0; q < 13; ++q) {
        uint4 wA = w4[q];
        const uint_t* pA = (const uint_t*)&wA;
        #pragma unroll
        for (int jj = 0; jj < 4; ++jj) {
          uint_t ua = s_tile[(q * 4 + jj) * 64 + lane];
          acc0 += bflo(pA[jj]) * bflo(ua) + bfhi(pA[jj]) * bfhi(ua);
        }
      }
    }
    __syncthreads();
  }

  if (isGate) {
    float gi = acc0 + gbias[hglob];
    float gf = acc1 + gbias[512 + hglob];
    float gg = acc2 + gbias[1024 + hglob];
    float go = acc3 + gbias[1536 + hglob];
    float c0 = g_c[(size_t)hglob * 64 + lane];
    float cn = sigf(gf) * c0 + sigf(gi) * tanhf(gg);
    float hn = sigf(go) * tanhf(cn);
    g_c[(size_t)hglob * 64 + lane] = cn;
    s_h[u * 64 + lane] = hn;
    __syncthreads();
    if (tid < 256) {
      int q = tid >> 6;
      float h0 = s_h[(2 * q) * 64 + lane], h1 = s_h[(2 * q + 1) * 64 + lane];
      int kp = 160 + 256 * (par ^ 1) + blk * 4 + q;
      A2[(size_t)kp * 64 + lane] = packbf(h0, h1);
    }
  } else {
    int j = orow - 2048;
    out[((size_t)lane * TT + (t - 1)) * DD + j] = sigf(acc0 + out_b[j]);
  }
}

// ============ K2: head projections GEMM (weight-stationary; proven R10) ============
__global__ __launch_bounds__(512) void k2_heads(
    int wslot, const uint_t* __restrict__ W2h,
    const float* __restrict__ read_b, const float* __restrict__ write_b,
    const uint_t* __restrict__ A2, float* __restrict__ g_headp) {
  const int blk = blockIdx.x, tid = threadIdx.x;
  const int lane = tid & 63, u = tid >> 6;
  const int r = blk * 8 + u;
  __shared__ uint_t s_tile[64 * 64];
  __shared__ float s_tr[8 * 65];
  const int hbase = 160 + 256 * wslot;
  float acc = 0.f;
  const uint_t* wrow = W2h + (size_t)r * 256;
  for (int c = 0; c < 4; ++c) {
    for (int i = tid; i < 64 * 64; i += 512) {
      int kk = i >> 6, bb = i & 63;
      s_tile[i] = A2[(size_t)(hbase + c * 64 + kk) * 64 + bb];
    }
    __syncthreads();
    #pragma unroll 4
    for (int kk = 0; kk < 64; ++kk) {
      uint_t ua = s_tile[kk * 64 + lane];
      uint_t w = wrow[c * 64 + kk];
      acc += bflo(w) * bflo(ua) + bfhi(w) * bfhi(ua);
    }
    __syncthreads();
  }
  acc += (r < 280) ? read_b[r] : write_b[r - 280];
  s_tr[u * 65 + lane] = acc;
  __syncthreads();
  if (tid < 128) {
    int bb = tid & 63, half = tid >> 6;
    float4 v;
    v.x = s_tr[(half * 4 + 0) * 65 + bb];
    v.y = s_tr[(half * 4 + 1) * 65 + bb];
    v.z = s_tr[(half * 4 + 2) * 65 + bb];
    v.w = s_tr[(half * 4 + 3) * 65 + bb];
    *(float4*)(g_headp + (size_t)bb * 1088 + blk * 8 + half * 4) = v;
  }
}

// ============ K3: per-batch memory phase — mem LDS-resident ============
// Dynamic LDS: 1024 rows x 32 uints, rotation-swizzled: slot(row,c) = (c+row)&31.
// launch_bounds(1024,4): 16 waves = 4/SIMD -> VGPR cap 128 (kills spills at 64).
__global__ __launch_bounds__(1024, 4) void k3_mem(
    int t, const float* __restrict__ x, const float* __restrict__ g_headp,
    ushort_t* __restrict__ g_mem, uint_t* __restrict__ A2,
    float* __restrict__ g_ws) {
  const int b = blockIdx.x, tid = threadIdx.x;
  const int lane = tid & 63, wave = tid >> 6;
  extern __shared__ uint_t s_mem[];            // 131072 B
  __shared__ alignas(16) float s_wgA[1024];    // wgR, then wR final
  __shared__ alignas(16) float s_wgB[1024];    // wgW, then wW final
  __shared__ alignas(16) float s_part[1024];
  __shared__ alignas(16) float s_reads[RR * VV];
  __shared__ alignas(16) float s_or[72];
  __shared__ alignas(16) float s_ow[200];
  __shared__ alignas(16) float s_e[VV];
  __shared__ alignas(16) float s_a[VV];
  __shared__ float s_redR[16];
  __shared__ float s_redW[16];
  uint_t* m32 = (uint_t*)(g_mem + (size_t)b * (NN * VV));
  const float* hp = g_headp + (size_t)b * 1088;

  for (int hd = 0; hd < RR; ++hd) {
    if (tid < 70) s_or[tid] = hp[hd * 70 + tid];
    else if (tid >= 128 && tid < 326) s_ow[tid - 128] = hp[280 + hd * 198 + (tid - 128)];
    __syncthreads();                              // S0
    if (tid < VV) { s_e[tid] = sigf(s_ow[70 + tid]); s_a[tid] = s_ow[134 + tid]; }

    float wprevR = g_ws[(size_t)(b * 8 + 2 * hd) * 1024 + tid];
    float wprevW = g_ws[(size_t)(b * 8 + 2 * hd + 1) * 1024 + tid];

    // ---- dot pass over own row (tid): dual keys (kk hoisted out) ----
    float dotR = 0.f, dotW = 0.f, nrm2 = 0.f;
    if (hd == 0) {
      // stream from EA (coalesced uint4) + deposit rotated into LDS
      const uint4* rowp = (const uint4*)(m32 + (size_t)tid * 32);
      const float4* orf = (const float4*)s_or;
      const float4* owf = (const float4*)s_ow;
      #pragma unroll
      for (int p = 0; p < 8; ++p) {
        uint4 m = rowp[p];
        s_mem[tid * 32 + ((4 * p + 0 + tid) & 31)] = m.x;
        s_mem[tid * 32 + ((4 * p + 1 + tid) & 31)] = m.y;
        s_mem[tid * 32 + ((4 * p + 2 + tid) & 31)] = m.z;
        s_mem[tid * 32 + ((4 * p + 3 + tid) & 31)] = m.w;
        float4 ka = orf[2 * p], kb = orf[2 * p + 1];
        float4 wa = owf[2 * p], wb = owf[2 * p + 1];
        float m0 = bflo(m.x), m1 = bfhi(m.x), m2 = bflo(m.y), m3 = bfhi(m.y);
        float m4 = bflo(m.z), m5 = bfhi(m.z), m6 = bflo(m.w), m7 = bfhi(m.w);
        nrm2 += m0 * m0 + m1 * m1 + m2 * m2 + m3 * m3 + m4 * m4 + m5 * m5 + m6 * m6 + m7 * m7;
        dotR += m0 * ka.x + m1 * ka.y + m2 * ka.z + m3 * ka.w +
                m4 * kb.x + m5 * kb.y + m6 * kb.z + m7 * kb.w;
        dotW += m0 * wa.x + m1 * wa.y + m2 * wa.z + m3 * wa.w +
                m4 * wb.x + m5 * wb.y + m6 * wb.z + m7 * wb.w;
      }
    } else {
      #pragma unroll 8
      for (int c = 0; c < 32; ++c) {
        uint_t u = s_mem[tid * 32 + ((c + tid) & 31)];
        float v0 = bflo(u), v1 = bfhi(u);
        nrm2 += v0 * v0 + v1 * v1;
        dotR += v0 * s_or[2 * c] + v1 * s_or[2 * c + 1];
        dotW += v0 * s_ow[2 * c] + v1 * s_ow[2 * c + 1];
      }
    }
    // ---- per-wave key-norm reduce (wave-uniform; replaces per-iter kk accumulate) ----
    float kkR, kkW;
    {
      float kR = s_or[lane]; kR *= kR;
      float kW = s_ow[lane]; kW *= kW;
      #pragma unroll
      for (int o = 32; o; o >>= 1) { kR += __shfl_xor(kR, o); kW += __shfl_xor(kW, o); }
      kkR = kR; kkW = kW;
    }
    float na = fmaxf(sqrtf(nrm2), 1e-8f);

    // ---- dual softmax chain ----
    float nbR = fmaxf(sqrtf(kkR), 1e-8f), nbW = fmaxf(sqrtf(kkW), 1e-8f);
    float betaR = splus(s_or[64]), betaW = splus(s_ow[64]);
    float gR = sigf(s_or[65]), gW = sigf(s_ow[65]);
    float r0 = s_or[66], r1 = s_or[67], r2 = s_or[68];
    float q0 = s_ow[66], q1 = s_ow[67], q2 = s_ow[68];
    float mxR = fmaxf(r0, fmaxf(r1, r2)), mxW = fmaxf(q0, fmaxf(q1, q2));
    float eR0 = __expf(r0 - mxR), eR1 = __expf(r1 - mxR), eR2 = __expf(r2 - mxR);
    float eW0 = __expf(q0 - mxW), eW1 = __expf(q1 - mxW), eW2 = __expf(q2 - mxW);
    float siR = 1.0f / (eR0 + eR1 + eR2), siW = 1.0f / (eW0 + eW1 + eW2);
    float gamR = 1.0f + splus(s_or[69]), gamW = 1.0f + splus(s_ow[69]);
    float eeR = __expf(betaR * dotR / (na * nbR));   // |z|<=beta: no max-sub
    float eeW = __expf(betaW * dotW / (na * nbW));
    float vR = eeR, vW = eeW;
    #pragma unroll
    for (int o = 32; o; o >>= 1) { vR += __shfl_xor(vR, o); vW += __shfl_xor(vW, o); }
    if (lane == 0) { s_redR[wave] = vR; s_redW[wave] = vW; }
    __syncthreads();                              // S1
    float SR = 0.f, SW = 0.f;
    #pragma unroll
    for (int w = 0; w < 16; ++w) { SR += s_redR[w]; SW += s_redW[w]; }
    float wgR = gR * (eeR / SR) + (1.0f - gR) * wprevR;
    float wgW = gW * (eeW / SW) + (1.0f - gW) * wprevW;
    s_wgA[tid] = wgR;
    s_wgB[tid] = wgW;
    __syncthreads();                              // S2
    int tm = (tid + 1023) & 1023, tp = (tid + 1) & 1023;
    float wsnR = (eR0 * siR) * s_wgA[tm] + (eR1 * siR) * s_wgA[tid] + (eR2 * siR) * s_wgA[tp];
    float wsnW = (eW0 * siW) * s_wgB[tm] + (eW1 * siW) * s_wgB[tid] + (eW2 * siW) * s_wgB[tp];
    float wpR = __expf(gamR * __logf(wsnR));
    float wpW = __expf(gamW * __logf(wsnW));
    vR = wpR; vW = wpW;
    #pragma unroll
    for (int o = 32; o; o >>= 1) { vR += __shfl_xor(vR, o); vW += __shfl_xor(vW, o); }
    if (lane == 0) { s_redR[wave] = vR; s_redW[wave] = vW; }
    __syncthreads();                              // S3 (all shift reads done)
    float ZR = 0.f, ZW = 0.f;
    #pragma unroll
    for (int w = 0; w < 16; ++w) { ZR += s_redR[w]; ZW += s_redW[w]; }
    float wRf = wpR / (ZR + 1e-16f);
    float wWf = wpW / (ZW + 1e-16f);
    s_wgA[tid] = wRf;
    s_wgB[tid] = wWf;
    g_ws[(size_t)(b * 8 + 2 * hd) * 1024 + tid] = wRf;
    g_ws[(size_t)(b * 8 + 2 * hd + 1) * 1024 + tid] = wWf;
    __syncthreads();                              // S4: wR/wW visible

    // ---- fused einsum + erase in LDS (head 3 erase -> EA) ----
    {
      const int cp = lane & 31, half = lane >> 5;
      const float e0 = s_e[2 * cp], e1 = s_e[2 * cp + 1];
      const float a0 = s_a[2 * cp], a1 = s_a[2 * cp + 1];
      const int rbase = wave * 64 + half;
      float acc0 = 0.f, acc1 = 0.f;
      #pragma unroll 8
      for (int q = 0; q < 32; ++q) {
        int row = rbase + 2 * q;
        int addr = row * 32 + ((cp + row) & 31);
        uint_t uu = s_mem[addr];
        float wRn = s_wgA[row];
        float wWn = s_wgB[row];
        float v0 = bflo(uu), v1 = bfhi(uu);
        acc0 += wRn * v0; acc1 += wRn * v1;
        float n0 = v0 * (1.f - wWn * e0) + wWn * a0;
        float n1 = v1 * (1.f - wWn * e1) + wWn * a1;
        uint_t nu = packbf(n0, n1);
        if (hd < 3) s_mem[addr] = nu;
        else        m32[(size_t)row * 32 + cp] = nu;   // final mem -> EA, coalesced
      }
      acc0 += __shfl_xor(acc0, 32);
      acc1 += __shfl_xor(acc1, 32);
      if (half == 0) *(float2*)(s_part + wave * 64 + 2 * cp) = make_float2(acc0, acc1);
    }
    __syncthreads();                              // S5
    if (tid < VV) {
      float s = 0.f;
      #pragma unroll
      for (int w2 = 0; w2 < 16; ++w2) s += s_part[w2 * 64 + tid];
      s_reads[hd * VV + tid] = s;
    }
  } // hd
  __syncthreads();

  // publish reads_t and x_{t+1} into A (bf16 pairs)
  if (tid < 128)
    A2[(size_t)(32 + tid) * 64 + b] = packbf(s_reads[2 * tid], s_reads[2 * tid + 1]);
  if (tid < 32 && t + 1 < TT) {
    float v0 = x[((size_t)b * TT + t + 1) * DD + 2 * tid];
    float v1 = x[((size_t)b * TT + t + 1) * DD + 2 * tid + 1];
    A2[(size_t)tid * 64 + b] = packbf(v0, v1);
  }
}

extern "C" void kernel_launch(void* const* d_in, const int* in_sizes, int n_in,
                              void* d_out, int out_size, void* d_ws, size_t ws_size,
                              hipStream_t stream) {
  char* ws = (char*)d_ws;
  ushort_t* g_mem = (ushort_t*)ws;                 //  8,388,608
  uint_t* g_A2    = (uint_t*)(ws + 8388608);       //    172,032
  float* g_c      = (float*)(ws + 8560640);        //    131,072
  float* g_ws     = (float*)(ws + 8691712);        //  2,097,152
  float* g_headp  = (float*)(ws + 10788864);       //    278,528
  uint_t* W2g     = (uint_t*)(ws + 11067392);      //  3,514,368
  uint_t* W2h     = (uint_t*)(ws + 14581760);      //  1,097,728
  float* gbias    = (float*)(ws + 15679488);       //      8,192  (~15.7 MB)

  const float* x        = (const float*)d_in[0];
  const float* mem_bias = (const float*)d_in[1];
  const float* h_bias   = (const float*)d_in[2];
  const float* c_bias   = (const float*)d_in[3];
  const float* W_ih     = (const float*)d_in[4];
  const float* W_hh     = (const float*)d_in[5];
  const float* b_ih     = (const float*)d_in[6];
  const float* b_hh     = (const float*)d_in[7];
  const float* read_W   = (const float*)d_in[8];
  const float* read_b   = (const float*)d_in[9];
  const float* write_W  = (const float*)d_in[10];
  const float* write_b  = (const float*)d_in[11];
  const float* read_init= (const float*)d_in[12];
  const float* out_W    = (const float*)d_in[13];
  const float* out_b    = (const float*)d_in[14];
  float* out = (float*)d_out;

  bias_kernel<<<8, 256, 0, stream>>>(b_ih, b_hh, gbias);
  build_gw<<<3432, 256, 0, stream>>>(W_ih, W_hh, out_W, W2g);
  build_hw<<<1072, 256, 0, stream>>>(read_W, write_W, W2h);
  k0_init<<<64, 1024, 0, stream>>>(x, mem_bias, h_bias, c_bias, read_init,
                                   g_mem, g_A2, g_c, g_ws);
  for (int t = 0; t < TT; ++t) {
    k1_gates<<<72, 512, 0, stream>>>(t, 64, t & 1, W2g, gbias, g_A2, g_c, out_b, out);
    k2_heads<<<134, 512, 0, stream>>>((t + 1) & 1, W2h, read_b, write_b, g_A2, g_headp);
    k3_mem<<<64, 1024, 131072, stream>>>(t, x, g_headp, g_mem, g_A2, g_ws);
  }
  // final out row batch: out(t=31) from h_31 (slot 0) + reads_31
  k1_gates<<<8, 512, 0, stream>>>(TT, 0, 0, W2g, gbias, g_A2, g_c, out_b, out);
}

// Round 17
// 3882.984 us; speedup vs baseline: 1.7343x; 1.1141x over previous
//
#include <hip/hip_runtime.h>
#include <math.h>

#define TT 32
#define DD 64
#define NN 1024
#define VV 64
#define RR 4
#define HH 512

typedef unsigned int uint_t;
typedef unsigned short ushort_t;

__device__ __forceinline__ float sigf(float x) { return 1.0f / (1.0f + __expf(-x)); }
__device__ __forceinline__ float splus(float x) {
  return (x > 0.f) ? (x + log1pf(__expf(-x))) : log1pf(__expf(x));
}
__device__ __forceinline__ ushort_t bfr(float f) {
  uint_t u = __float_as_uint(f);
  return (ushort_t)((u + 0x7fffu + ((u >> 16) & 1u)) >> 16);
}
__device__ __forceinline__ float bflo(uint_t u) { return __uint_as_float(u << 16); }
__device__ __forceinline__ float bfhi(uint_t u) { return __uint_as_float(u & 0xffff0000u); }
__device__ __forceinline__ uint_t packbf(float a, float b) {
  return (uint_t)bfr(a) | ((uint_t)bfr(b) << 16);
}

// ============ pre-kernels (every launch; deterministic) ============
__global__ void build_gw(const float* __restrict__ W_ih, const float* __restrict__ W_hh,
                         const float* __restrict__ out_W, uint_t* __restrict__ W2g) {
  int idx = blockIdx.x * 256 + threadIdx.x;           // 2112*416
  if (idx >= 2112 * 416) return;
  int r = idx / 416, kp = idx - r * 416;
  float v[2];
  #pragma unroll
  for (int q = 0; q < 2; ++q) {
    int k = 2 * kp + q;
    float f;
    if (r < 2048) {
      int h = r >> 2, g = r & 3, row = g * 512 + h;
      f = (k < 320) ? W_ih[(size_t)row * 320 + k] : W_hh[(size_t)row * 512 + (k - 320)];
    } else {
      int j = r - 2048;
      if (k < 64) f = 0.f;
      else if (k < 320) f = out_W[(size_t)j * 768 + 512 + (k - 64)];
      else f = out_W[(size_t)j * 768 + (k - 320)];
    }
    v[q] = f;
  }
  W2g[idx] = packbf(v[0], v[1]);
}
__global__ void build_hw(const float* __restrict__ read_W, const float* __restrict__ write_W,
                         uint_t* __restrict__ W2h) {
  int idx = blockIdx.x * 256 + threadIdx.x;           // 1072*256
  if (idx >= 1072 * 256) return;
  int r = idx >> 8, kp = idx & 255;
  const float* src = (r < 280) ? (read_W + (size_t)r * 512) : (write_W + (size_t)(r - 280) * 512);
  W2h[idx] = packbf(src[2 * kp], src[2 * kp + 1]);
}
__global__ void bias_kernel(const float* __restrict__ bi, const float* __restrict__ bh,
                            float* __restrict__ o) {
  int i = blockIdx.x * 256 + threadIdx.x;
  if (i < 2048) o[i] = bi[i] + bh[i];
}
__global__ void k0_init(const float* __restrict__ x, const float* __restrict__ mem_bias,
                        const float* __restrict__ h_bias, const float* __restrict__ c_bias,
                        const float* __restrict__ read_init,
                        ushort_t* __restrict__ g_mem, uint_t* __restrict__ A2,
                        float* __restrict__ g_c, float* __restrict__ g_ws) {
  const int b = blockIdx.x, tid = threadIdx.x;
  {
    const float4* src = (const float4*)(mem_bias + (size_t)tid * VV);
    uint4* dst = (uint4*)(g_mem + (size_t)b * (NN * VV) + (size_t)tid * VV);
    #pragma unroll
    for (int p = 0; p < 8; ++p) {
      float4 va = src[2 * p], vb = src[2 * p + 1];
      uint4 o;
      o.x = packbf(va.x, va.y); o.y = packbf(va.z, va.w);
      o.z = packbf(vb.x, vb.y); o.w = packbf(vb.z, vb.w);
      dst[p] = o;
    }
  }
  if (tid < 416) {
    float v0, v1;
    if (tid < 32)      { v0 = x[((size_t)b * TT) * DD + 2 * tid]; v1 = x[((size_t)b * TT) * DD + 2 * tid + 1]; }
    else if (tid < 160){ int e = 2 * (tid - 32); v0 = read_init[e]; v1 = read_init[e + 1]; }
    else               { int e = 2 * (tid - 160); v0 = h_bias[e]; v1 = h_bias[e + 1]; }
    A2[(size_t)tid * 64 + b] = packbf(v0, v1);
  }
  if (tid < 512) g_c[(size_t)tid * 64 + b] = c_bias[tid];
  for (int i = tid; i < 8192; i += 1024) g_ws[(size_t)b * 8192 + i] = 0.f;
}

// ============ K1s: gates+out GEMM, split-K x2 (partials) ============
// blocks 0..127: gate half (grp=blk>>1, kh=blk&1, 8 h-rows x 4 gates)
// blocks 128..143: out half (grp=(blk-128)>>1, kh=(blk-128)&1, 8 out rows)
__global__ __launch_bounds__(512) void k1s(
    int par, int doGate, int doOut,
    const uint_t* __restrict__ W2g, const uint_t* __restrict__ A2,
    float* __restrict__ g_gp) {
  const int blk = blockIdx.x, tid = threadIdx.x;
  const int lane = tid & 63, u = tid >> 6;
  const bool isGate = (blk < 128);
  if (isGate && !doGate) return;
  if (!isGate && !doOut) return;
  __shared__ uint_t s_tile[52 * 64];
  int kh, hglob = 0, orow = 0;
  size_t wbase;
  if (isGate) {
    int grp = blk >> 1; kh = blk & 1;
    hglob = grp * 8 + u;
    wbase = (size_t)(hglob * 4) * 416;
  } else {
    int ob = blk - 128; kh = ob & 1;
    orow = 2048 + (ob >> 1) * 8 + u;
    wbase = (size_t)orow * 416;
  }
  float acc0 = 0.f, acc1 = 0.f, acc2 = 0.f, acc3 = 0.f;
  for (int cc = 0; cc < 4; ++cc) {
    int c = kh * 4 + cc;
    for (int i = tid; i < 52 * 64; i += 512) {
      int kk = i >> 6, bb = i & 63;
      int kpg = c * 52 + kk;
      int phys = (kpg < 160) ? kpg : kpg + 256 * par;
      s_tile[i] = A2[(size_t)phys * 64 + bb];
    }
    __syncthreads();
    const uint4* w4 = (const uint4*)(W2g + wbase) + c * 13;
    if (isGate) {
      #pragma unroll
      for (int q = 0; q < 13; ++q) {
        uint4 wA = w4[q], wB = w4[104 + q], wC = w4[208 + q], wD = w4[312 + q];
        const uint_t* pA = (const uint_t*)&wA;
        const uint_t* pB = (const uint_t*)&wB;
        const uint_t* pC = (const uint_t*)&wC;
        const uint_t* pD = (const uint_t*)&wD;
        #pragma unroll
        for (int jj = 0; jj < 4; ++jj) {
          uint_t ua = s_tile[(q * 4 + jj) * 64 + lane];
          float a0 = bflo(ua), a1 = bfhi(ua);
          acc0 += bflo(pA[jj]) * a0 + bfhi(pA[jj]) * a1;
          acc1 += bflo(pB[jj]) * a0 + bfhi(pB[jj]) * a1;
          acc2 += bflo(pC[jj]) * a0 + bfhi(pC[jj]) * a1;
          acc3 += bflo(pD[jj]) * a0 + bfhi(pD[jj]) * a1;
        }
      }
    } else {
      #pragma unroll
      for (int q = 0; q < 13; ++q) {
        uint4 wA = w4[q];
        const uint_t* pA = (const uint_t*)&wA;
        #pragma unroll
        for (int jj = 0; jj < 4; ++jj) {
          uint_t ua = s_tile[(q * 4 + jj) * 64 + lane];
          acc0 += bflo(pA[jj]) * bflo(ua) + bfhi(pA[jj]) * bfhi(ua);
        }
      }
    }
    __syncthreads();
  }
  if (isGate) {
    float* d = g_gp + (size_t)(kh * 2112 + hglob * 4) * 64 + lane;
    d[0] = acc0; d[64] = acc1; d[128] = acc2; d[192] = acc3;
  } else {
    g_gp[(size_t)(kh * 2112 + orow) * 64 + lane] = acc0;
  }
}

// ============ K1c: combine + LSTM + h publish + out write ============
__global__ __launch_bounds__(512) void k1c(
    int t, int par, int doGate,
    const float* __restrict__ g_gp, const float* __restrict__ gbias,
    uint_t* __restrict__ A2, float* __restrict__ g_c,
    const float* __restrict__ out_b, float* __restrict__ out) {
  const int blk = blockIdx.x, tid = threadIdx.x;
  const int lane = tid & 63, u = tid >> 6;
  if (blk < 64) {
    if (!doGate) return;
    __shared__ float s_h[512];
    const int hglob = blk * 8 + u;
    const float* p0 = g_gp + (size_t)(hglob * 4) * 64 + lane;
    const float* p1 = g_gp + (size_t)(2112 + hglob * 4) * 64 + lane;
    float gi = gbias[hglob]        + p0[0]   + p1[0];
    float gf = gbias[512 + hglob]  + p0[64]  + p1[64];
    float gg = gbias[1024 + hglob] + p0[128] + p1[128];
    float go = gbias[1536 + hglob] + p0[192] + p1[192];
    float c0 = g_c[(size_t)hglob * 64 + lane];
    float cn = sigf(gf) * c0 + sigf(gi) * tanhf(gg);
    float hn = sigf(go) * tanhf(cn);
    g_c[(size_t)hglob * 64 + lane] = cn;
    s_h[u * 64 + lane] = hn;
    __syncthreads();
    if (tid < 256) {
      int q = tid >> 6;
      float h0 = s_h[(2 * q) * 64 + lane], h1 = s_h[(2 * q + 1) * 64 + lane];
      int kp = 160 + 256 * (par ^ 1) + blk * 4 + q;
      A2[(size_t)kp * 64 + lane] = packbf(h0, h1);
    }
  } else {
    if (t == 0) return;
    int j = (blk - 64) * 8 + u;
    float v = out_b[j] + g_gp[(size_t)(2048 + j) * 64 + lane]
                       + g_gp[(size_t)(2112 + 2048 + j) * 64 + lane];
    out[((size_t)lane * TT + (t - 1)) * DD + j] = sigf(v);
  }
}

// ============ K2: head projections GEMM, split-K x2 ============
__global__ __launch_bounds__(512) void k2_heads(
    int wslot, const uint_t* __restrict__ W2h,
    const float* __restrict__ read_b, const float* __restrict__ write_b,
    const uint_t* __restrict__ A2, float* __restrict__ g_headp) {
  const int blk = blockIdx.x, tid = threadIdx.x;
  const int lane = tid & 63, u = tid >> 6;
  const int rgrp = blk >> 1, kh = blk & 1;
  const int r = rgrp * 8 + u;
  __shared__ uint_t s_tile[64 * 64];
  __shared__ float s_tr[8 * 65];
  const int hbase = 160 + 256 * wslot + kh * 128;
  float acc = 0.f;
  const uint_t* wrow = W2h + (size_t)r * 256 + kh * 128;
  for (int c = 0; c < 2; ++c) {
    for (int i = tid; i < 64 * 64; i += 512) {
      int kk = i >> 6, bb = i & 63;
      s_tile[i] = A2[(size_t)(hbase + c * 64 + kk) * 64 + bb];
    }
    __syncthreads();
    #pragma unroll 4
    for (int kk = 0; kk < 64; ++kk) {
      uint_t ua = s_tile[kk * 64 + lane];
      uint_t w = wrow[c * 64 + kk];
      acc += bflo(w) * bflo(ua) + bfhi(w) * bfhi(ua);
    }
    __syncthreads();
  }
  if (kh == 0) acc += (r < 280) ? read_b[r] : write_b[r - 280];
  s_tr[u * 65 + lane] = acc;
  __syncthreads();
  if (tid < 128) {
    int bb = tid & 63, half = tid >> 6;
    float4 v;
    v.x = s_tr[(half * 4 + 0) * 65 + bb];
    v.y = s_tr[(half * 4 + 1) * 65 + bb];
    v.z = s_tr[(half * 4 + 2) * 65 + bb];
    v.w = s_tr[(half * 4 + 3) * 65 + bb];
    *(float4*)(g_headp + (size_t)kh * 69632 + (size_t)bb * 1088 + rgrp * 8 + half * 4) = v;
  }
}

// ============ K3: per-batch memory phase — mem LDS-resident ============
// Dynamic LDS: 1024 rows x 32 uints, rotation-swizzled: slot(row,c) = (c+row)&31.
__global__ __launch_bounds__(1024, 4) void k3_mem(
    int t, const float* __restrict__ x, const float* __restrict__ g_headp,
    ushort_t* __restrict__ g_mem, uint_t* __restrict__ A2,
    float* __restrict__ g_ws) {
  const int b = blockIdx.x, tid = threadIdx.x;
  const int lane = tid & 63, wave = tid >> 6;
  extern __shared__ uint_t s_mem[];            // 131072 B
  __shared__ alignas(16) float s_wgA[1024];    // wgR, then wR final
  __shared__ alignas(16) float s_wgB[1024];    // wgW, then wW final
  __shared__ alignas(16) float s_part[1024];
  __shared__ alignas(16) float s_reads[RR * VV];
  __shared__ alignas(16) float s_or[72];
  __shared__ alignas(16) float s_ow[200];
  __shared__ alignas(16) float s_e[VV];
  __shared__ alignas(16) float s_a[VV];
  __shared__ float s_redR[16];
  __shared__ float s_redW[16];
  uint_t* m32 = (uint_t*)(g_mem + (size_t)b * (NN * VV));
  const float* hp = g_headp + (size_t)b * 1088;
  const float* hp1 = hp + 69632;

  // ---- prefetch ws history into registers ----
  float wsr[8];
  #pragma unroll
  for (int s2 = 0; s2 < 8; ++s2) wsr[s2] = g_ws[(size_t)(b * 8 + s2) * 1024 + tid];

  // ---- proj load head 0 (sum split-K halves) ----
  if (tid < 70) s_or[tid] = hp[tid] + hp1[tid];
  else if (tid >= 128 && tid < 326) s_ow[tid - 128] = hp[280 + (tid - 128)] + hp1[280 + (tid - 128)];
  __syncthreads();                              // P0
  if (tid < VV) { s_e[tid] = sigf(s_ow[70 + tid]); s_a[tid] = s_ow[134 + tid]; }

  for (int hd = 0; hd < RR; ++hd) {
    // ---- dot pass over own row (tid): dual keys ----
    float dotR = 0.f, dotW = 0.f, nrm2 = 0.f;
    if (hd == 0) {
      const uint4* rowp = (const uint4*)(m32 + (size_t)tid * 32);
      const float4* orf = (const float4*)s_or;
      const float4* owf = (const float4*)s_ow;
      #pragma unroll
      for (int p = 0; p < 8; ++p) {
        uint4 m = rowp[p];
        s_mem[tid * 32 + ((4 * p + 0 + tid) & 31)] = m.x;
        s_mem[tid * 32 + ((4 * p + 1 + tid) & 31)] = m.y;
        s_mem[tid * 32 + ((4 * p + 2 + tid) & 31)] = m.z;
        s_mem[tid * 32 + ((4 * p + 3 + tid) & 31)] = m.w;
        float4 ka = orf[2 * p], kb = orf[2 * p + 1];
        float4 wa = owf[2 * p], wb = owf[2 * p + 1];
        float m0 = bflo(m.x), m1 = bfhi(m.x), m2 = bflo(m.y), m3 = bfhi(m.y);
        float m4 = bflo(m.z), m5 = bfhi(m.z), m6 = bflo(m.w), m7 = bfhi(m.w);
        nrm2 += m0 * m0 + m1 * m1 + m2 * m2 + m3 * m3 + m4 * m4 + m5 * m5 + m6 * m6 + m7 * m7;
        dotR += m0 * ka.x + m1 * ka.y + m2 * ka.z + m3 * ka.w +
                m4 * kb.x + m5 * kb.y + m6 * kb.z + m7 * kb.w;
        dotW += m0 * wa.x + m1 * wa.y + m2 * wa.z + m3 * wa.w +
                m4 * wb.x + m5 * wb.y + m6 * wb.z + m7 * wb.w;
      }
    } else {
      #pragma unroll 8
      for (int c = 0; c < 32; ++c) {
        uint_t u = s_mem[tid * 32 + ((c + tid) & 31)];
        float v0 = bflo(u), v1 = bfhi(u);
        nrm2 += v0 * v0 + v1 * v1;
        dotR += v0 * s_or[2 * c] + v1 * s_or[2 * c + 1];
        dotW += v0 * s_ow[2 * c] + v1 * s_ow[2 * c + 1];
      }
    }
    // ---- per-wave key-norm reduce ----
    float kkR, kkW;
    {
      float kR = s_or[lane]; kR *= kR;
      float kW = s_ow[lane]; kW *= kW;
      #pragma unroll
      for (int o = 32; o; o >>= 1) { kR += __shfl_xor(kR, o); kW += __shfl_xor(kW, o); }
      kkR = kR; kkW = kW;
    }
    float na = fmaxf(sqrtf(nrm2), 1e-8f);

    // ---- dual softmax chain ----
    float nbR = fmaxf(sqrtf(kkR), 1e-8f), nbW = fmaxf(sqrtf(kkW), 1e-8f);
    float betaR = splus(s_or[64]), betaW = splus(s_ow[64]);
    float gR = sigf(s_or[65]), gW = sigf(s_ow[65]);
    float r0 = s_or[66], r1 = s_or[67], r2 = s_or[68];
    float q0 = s_ow[66], q1 = s_ow[67], q2 = s_ow[68];
    float mxR = fmaxf(r0, fmaxf(r1, r2)), mxW = fmaxf(q0, fmaxf(q1, q2));
    float eR0 = __expf(r0 - mxR), eR1 = __expf(r1 - mxR), eR2 = __expf(r2 - mxR);
    float eW0 = __expf(q0 - mxW), eW1 = __expf(q1 - mxW), eW2 = __expf(q2 - mxW);
    float siR = 1.0f / (eR0 + eR1 + eR2), siW = 1.0f / (eW0 + eW1 + eW2);
    float gamR = 1.0f + splus(s_or[69]), gamW = 1.0f + splus(s_ow[69]);
    float eeR = __expf(betaR * dotR / (na * nbR));   // |z|<=beta: no max-sub
    float eeW = __expf(betaW * dotW / (na * nbW));
    float vR = eeR, vW = eeW;
    #pragma unroll
    for (int o = 32; o; o >>= 1) { vR += __shfl_xor(vR, o); vW += __shfl_xor(vW, o); }
    if (lane == 0) { s_redR[wave] = vR; s_redW[wave] = vW; }
    __syncthreads();                              // S1
    float SR = 0.f, SW = 0.f;
    #pragma unroll
    for (int w = 0; w < 16; ++w) { SR += s_redR[w]; SW += s_redW[w]; }
    float wgR = gR * (eeR / SR) + (1.0f - gR) * wsr[2 * hd];
    float wgW = gW * (eeW / SW) + (1.0f - gW) * wsr[2 * hd + 1];
    s_wgA[tid] = wgR;
    s_wgB[tid] = wgW;
    __syncthreads();                              // S2
    int tm = (tid + 1023) & 1023, tp = (tid + 1) & 1023;
    float wsnR = (eR0 * siR) * s_wgA[tm] + (eR1 * siR) * s_wgA[tid] + (eR2 * siR) * s_wgA[tp];
    float wsnW = (eW0 * siW) * s_wgB[tm] + (eW1 * siW) * s_wgB[tid] + (eW2 * siW) * s_wgB[tp];
    float wpR = __expf(gamR * __logf(wsnR));
    float wpW = __expf(gamW * __logf(wsnW));
    vR = wpR; vW = wpW;
    #pragma unroll
    for (int o = 32; o; o >>= 1) { vR += __shfl_xor(vR, o); vW += __shfl_xor(vW, o); }
    if (lane == 0) { s_redR[wave] = vR; s_redW[wave] = vW; }
    __syncthreads();                              // S3
    float ZR = 0.f, ZW = 0.f;
    #pragma unroll
    for (int w = 0; w < 16; ++w) { ZR += s_redR[w]; ZW += s_redW[w]; }
    float wRf = wpR / (ZR + 1e-16f);
    float wWf = wpW / (ZW + 1e-16f);
    s_wgA[tid] = wRf;
    s_wgB[tid] = wWf;
    g_ws[(size_t)(b * 8 + 2 * hd) * 1024 + tid] = wRf;
    g_ws[(size_t)(b * 8 + 2 * hd + 1) * 1024 + tid] = wWf;
    __syncthreads();                              // S4: wR/wW visible; s_or/s_ow dead

    // ---- prefetch next head's projections (hidden under einsum) ----
    if (hd < 3) {
      if (tid < 70) s_or[tid] = hp[(hd + 1) * 70 + tid] + hp1[(hd + 1) * 70 + tid];
      else if (tid >= 128 && tid < 326) {
        int i2 = tid - 128;
        s_ow[i2] = hp[280 + (hd + 1) * 198 + i2] + hp1[280 + (hd + 1) * 198 + i2];
      }
    }

    // ---- fused einsum + erase in LDS (head 3 erase -> EA) ----
    {
      const int cp = lane & 31, half = lane >> 5;
      const float e0 = s_e[2 * cp], e1 = s_e[2 * cp + 1];
      const float a0 = s_a[2 * cp], a1 = s_a[2 * cp + 1];
      const int rbase = wave * 64 + half;
      float acc0 = 0.f, acc1 = 0.f;
      #pragma unroll 8
      for (int q = 0; q < 32; ++q) {
        int row = rbase + 2 * q;
        int addr = row * 32 + ((cp + row) & 31);
        uint_t uu = s_mem[addr];
        float wRn = s_wgA[row];
        float wWn = s_wgB[row];
        float v0 = bflo(uu), v1 = bfhi(uu);
        acc0 += wRn * v0; acc1 += wRn * v1;
        float n0 = v0 * (1.f - wWn * e0) + wWn * a0;
        float n1 = v1 * (1.f - wWn * e1) + wWn * a1;
        uint_t nu = packbf(n0, n1);
        if (hd < 3) s_mem[addr] = nu;
        else        m32[(size_t)row * 32 + cp] = nu;   // final mem -> EA, coalesced
      }
      acc0 += __shfl_xor(acc0, 32);
      acc1 += __shfl_xor(acc1, 32);
      if (half == 0) *(float2*)(s_part + wave * 64 + 2 * cp) = make_float2(acc0, acc1);
    }
    __syncthreads();                              // S5
    if (tid < VV) {
      float s = 0.f;
      #pragma unroll
      for (int w2 = 0; w2 < 16; ++w2) s += s_part[w2 * 64 + tid];
      s_reads[hd * VV + tid] = s;
      if (hd < 3) { s_e[tid] = sigf(s_ow[70 + tid]); s_a[tid] = s_ow[134 + tid]; }
    }
  } // hd
  __syncthreads();

  // publish reads_t and x_{t+1} into A (bf16 pairs)
  if (tid < 128)
    A2[(size_t)(32 + tid) * 64 + b] = packbf(s_reads[2 * tid], s_reads[2 * tid + 1]);
  if (tid < 32 && t + 1 < TT) {
    float v0 = x[((size_t)b * TT + t + 1) * DD + 2 * tid];
    float v1 = x[((size_t)b * TT + t + 1) * DD + 2 * tid + 1];
    A2[(size_t)tid * 64 + b] = packbf(v0, v1);
  }
}

extern "C" void kernel_launch(void* const* d_in, const int* in_sizes, int n_in,
                              void* d_out, int out_size, void* d_ws, size_t ws_size,
                              hipStream_t stream) {
  char* ws = (char*)d_ws;
  ushort_t* g_mem = (ushort_t*)ws;                 //  8,388,608
  uint_t* g_A2    = (uint_t*)(ws + 8388608);       //    172,032
  float* g_c      = (float*)(ws + 8560640);        //    131,072
  float* g_ws     = (float*)(ws + 8691712);        //  2,097,152
  float* g_headp  = (float*)(ws + 10788864);       //    557,056 (2 halves)
  uint_t* W2g     = (uint_t*)(ws + 11345920);      //  3,514,368
  uint_t* W2h     = (uint_t*)(ws + 14860288);      //  1,097,728
  float* gbias    = (float*)(ws + 15958016);       //      8,192
  float* g_gp     = (float*)(ws + 15966208);       //  1,081,344  (~17.0 MB)

  const float* x        = (const float*)d_in[0];
  const float* mem_bias = (const float*)d_in[1];
  const float* h_bias   = (const float*)d_in[2];
  const float* c_bias   = (const float*)d_in[3];
  const float* W_ih     = (const float*)d_in[4];
  const float* W_hh     = (const float*)d_in[5];
  const float* b_ih     = (const float*)d_in[6];
  const float* b_hh     = (const float*)d_in[7];
  const float* read_W   = (const float*)d_in[8];
  const float* read_b   = (const float*)d_in[9];
  const float* write_W  = (const float*)d_in[10];
  const float* write_b  = (const float*)d_in[11];
  const float* read_init= (const float*)d_in[12];
  const float* out_W    = (const float*)d_in[13];
  const float* out_b    = (const float*)d_in[14];
  float* out = (float*)d_out;

  bias_kernel<<<8, 256, 0, stream>>>(b_ih, b_hh, gbias);
  build_gw<<<3432, 256, 0, stream>>>(W_ih, W_hh, out_W, W2g);
  build_hw<<<1072, 256, 0, stream>>>(read_W, write_W, W2h);
  k0_init<<<64, 1024, 0, stream>>>(x, mem_bias, h_bias, c_bias, read_init,
                                   g_mem, g_A2, g_c, g_ws);
  for (int t = 0; t < TT; ++t) {
    k1s<<<144, 512, 0, stream>>>(t & 1, 1, (t > 0) ? 1 : 0, W2g, g_A2, g_gp);
    k1c<<<72, 512, 0, stream>>>(t, t & 1, 1, g_gp, gbias, g_A2, g_c, out_b, out);
    k2_heads<<<268, 512, 0, stream>>>((t + 1) & 1, W2h, read_b, write_b, g_A2, g_headp);
    k3_mem<<<64, 1024, 131072, stream>>>(t, x, g_headp, g_mem, g_A2, g_ws);
  }
  // final out(t=31): out partials from h_31 (slot 0) + reads_31, then combine
  k1s<<<144, 512, 0, stream>>>(0, 0, 1, W2g, g_A2, g_gp);
  k1c<<<72, 512, 0, stream>>>(TT, 0, 0, g_gp, gbias, g_A2, g_c, out_b, out);
}

// Round 18
// 3277.714 us; speedup vs baseline: 2.0545x; 1.1847x over previous
//
#include <hip/hip_runtime.h>
#include <math.h>

#define TT 32
#define DD 64
#define NN 1024
#define VV 64
#define RR 4
#define HH 512

typedef unsigned int uint_t;
typedef unsigned short ushort_t;

__device__ __forceinline__ float sigf(float x) { return 1.0f / (1.0f + __expf(-x)); }
__device__ __forceinline__ float splus(float x) {
  return (x > 0.f) ? (x + log1pf(__expf(-x))) : log1pf(__expf(x));
}
__device__ __forceinline__ ushort_t bfr(float f) {
  uint_t u = __float_as_uint(f);
  return (ushort_t)((u + 0x7fffu + ((u >> 16) & 1u)) >> 16);
}
__device__ __forceinline__ float bflo(uint_t u) { return __uint_as_float(u << 16); }
__device__ __forceinline__ float bfhi(uint_t u) { return __uint_as_float(u & 0xffff0000u); }
__device__ __forceinline__ uint_t packbf(float a, float b) {
  return (uint_t)bfr(a) | ((uint_t)bfr(b) << 16);
}

// ============ pre-kernels (every launch; deterministic) ============
__global__ void build_gw(const float* __restrict__ W_ih, const float* __restrict__ W_hh,
                         const float* __restrict__ out_W, uint_t* __restrict__ W2g) {
  int idx = blockIdx.x * 256 + threadIdx.x;           // 2112*416
  if (idx >= 2112 * 416) return;
  int r = idx / 416, kp = idx - r * 416;
  float v[2];
  #pragma unroll
  for (int q = 0; q < 2; ++q) {
    int k = 2 * kp + q;
    float f;
    if (r < 2048) {
      int h = r >> 2, g = r & 3, row = g * 512 + h;
      f = (k < 320) ? W_ih[(size_t)row * 320 + k] : W_hh[(size_t)row * 512 + (k - 320)];
    } else {
      int j = r - 2048;
      if (k < 64) f = 0.f;
      else if (k < 320) f = out_W[(size_t)j * 768 + 512 + (k - 64)];
      else f = out_W[(size_t)j * 768 + (k - 320)];
    }
    v[q] = f;
  }
  W2g[idx] = packbf(v[0], v[1]);
}
__global__ void build_hw(const float* __restrict__ read_W, const float* __restrict__ write_W,
                         uint_t* __restrict__ W2h) {
  int idx = blockIdx.x * 256 + threadIdx.x;           // 1072*256
  if (idx >= 1072 * 256) return;
  int r = idx >> 8, kp = idx & 255;
  const float* src = (r < 280) ? (read_W + (size_t)r * 512) : (write_W + (size_t)(r - 280) * 512);
  W2h[idx] = packbf(src[2 * kp], src[2 * kp + 1]);
}
__global__ void bias_kernel(const float* __restrict__ bi, const float* __restrict__ bh,
                            float* __restrict__ o) {
  int i = blockIdx.x * 256 + threadIdx.x;
  if (i < 2048) o[i] = bi[i] + bh[i];
}
__global__ void k0_init(const float* __restrict__ x, const float* __restrict__ mem_bias,
                        const float* __restrict__ h_bias, const float* __restrict__ c_bias,
                        const float* __restrict__ read_init,
                        ushort_t* __restrict__ g_mem, uint_t* __restrict__ A2,
                        float* __restrict__ g_c, float* __restrict__ g_ws) {
  const int b = blockIdx.x, tid = threadIdx.x;
  {
    const float4* src = (const float4*)(mem_bias + (size_t)tid * VV);
    uint4* dst = (uint4*)(g_mem + (size_t)b * (NN * VV) + (size_t)tid * VV);
    #pragma unroll
    for (int p = 0; p < 8; ++p) {
      float4 va = src[2 * p], vb = src[2 * p + 1];
      uint4 o;
      o.x = packbf(va.x, va.y); o.y = packbf(va.z, va.w);
      o.z = packbf(vb.x, vb.y); o.w = packbf(vb.z, vb.w);
      dst[p] = o;
    }
  }
  if (tid < 416) {
    float v0, v1;
    if (tid < 32)      { v0 = x[((size_t)b * TT) * DD + 2 * tid]; v1 = x[((size_t)b * TT) * DD + 2 * tid + 1]; }
    else if (tid < 160){ int e = 2 * (tid - 32); v0 = read_init[e]; v1 = read_init[e + 1]; }
    else               { int e = 2 * (tid - 160); v0 = h_bias[e]; v1 = h_bias[e + 1]; }
    A2[(size_t)tid * 64 + b] = packbf(v0, v1);
  }
  if (tid < 512) g_c[(size_t)tid * 64 + b] = c_bias[tid];
  for (int i = tid; i < 8192; i += 1024) g_ws[(size_t)b * 8192 + i] = 0.f;
}

// ============ K1s: gates+out GEMM, split-K x4 (partials) ============
// blocks 0..255: gate (grp=blk>>2, kh=blk&3); blocks 256..287: out rows
__global__ __launch_bounds__(512) void k1s(
    int par, int doGate, int doOut,
    const uint_t* __restrict__ W2g, const uint_t* __restrict__ A2,
    float* __restrict__ g_gp) {
  const int blk = blockIdx.x, tid = threadIdx.x;
  const int lane = tid & 63, u = tid >> 6;
  const bool isGate = (blk < 256);
  if (isGate && !doGate) return;
  if (!isGate && !doOut) return;
  __shared__ uint_t s_tile[52 * 64];
  int kh, hglob = 0, orow = 0;
  size_t wbase;
  if (isGate) {
    int grp = blk >> 2; kh = blk & 3;
    hglob = grp * 8 + u;
    wbase = (size_t)(hglob * 4) * 416;
  } else {
    int ob = blk - 256; kh = ob & 3;
    orow = 2048 + (ob >> 2) * 8 + u;
    wbase = (size_t)orow * 416;
  }
  float acc0 = 0.f, acc1 = 0.f, acc2 = 0.f, acc3 = 0.f;
  for (int cc = 0; cc < 2; ++cc) {
    int c = kh * 2 + cc;
    for (int i = tid; i < 52 * 64; i += 512) {
      int kk = i >> 6, bb = i & 63;
      int kpg = c * 52 + kk;
      int phys = (kpg < 160) ? kpg : kpg + 256 * par;
      s_tile[i] = A2[(size_t)phys * 64 + bb];
    }
    __syncthreads();
    const uint4* w4 = (const uint4*)(W2g + wbase) + c * 13;
    if (isGate) {
      #pragma unroll
      for (int q = 0; q < 13; ++q) {
        uint4 wA = w4[q], wB = w4[104 + q], wC = w4[208 + q], wD = w4[312 + q];
        const uint_t* pA = (const uint_t*)&wA;
        const uint_t* pB = (const uint_t*)&wB;
        const uint_t* pC = (const uint_t*)&wC;
        const uint_t* pD = (const uint_t*)&wD;
        #pragma unroll
        for (int jj = 0; jj < 4; ++jj) {
          uint_t ua = s_tile[(q * 4 + jj) * 64 + lane];
          float a0 = bflo(ua), a1 = bfhi(ua);
          acc0 += bflo(pA[jj]) * a0 + bfhi(pA[jj]) * a1;
          acc1 += bflo(pB[jj]) * a0 + bfhi(pB[jj]) * a1;
          acc2 += bflo(pC[jj]) * a0 + bfhi(pC[jj]) * a1;
          acc3 += bflo(pD[jj]) * a0 + bfhi(pD[jj]) * a1;
        }
      }
    } else {
      #pragma unroll
      for (int q = 0; q < 13; ++q) {
        uint4 wA = w4[q];
        const uint_t* pA = (const uint_t*)&wA;
        #pragma unroll
        for (int jj = 0; jj < 4; ++jj) {
          uint_t ua = s_tile[(q * 4 + jj) * 64 + lane];
          acc0 += bflo(pA[jj]) * bflo(ua) + bfhi(pA[jj]) * bfhi(ua);
        }
      }
    }
    __syncthreads();
  }
  if (isGate) {
    float* d = g_gp + (size_t)kh * 135168 + (size_t)(hglob * 4) * 64 + lane;
    d[0] = acc0; d[64] = acc1; d[128] = acc2; d[192] = acc3;
  } else {
    g_gp[(size_t)kh * 135168 + (size_t)orow * 64 + lane] = acc0;
  }
}

// ============ K1c: combine(4) + LSTM + h publish + out write ============
__global__ __launch_bounds__(512) void k1c(
    int t, int par, int doGate,
    const float* __restrict__ g_gp, const float* __restrict__ gbias,
    uint_t* __restrict__ A2, float* __restrict__ g_c,
    const float* __restrict__ out_b, float* __restrict__ out) {
  const int blk = blockIdx.x, tid = threadIdx.x;
  const int lane = tid & 63, u = tid >> 6;
  if (blk < 64) {
    if (!doGate) return;
    __shared__ float s_h[512];
    const int hglob = blk * 8 + u;
    float gi = gbias[hglob], gf = gbias[512 + hglob];
    float gg = gbias[1024 + hglob], go = gbias[1536 + hglob];
    #pragma unroll
    for (int kh = 0; kh < 4; ++kh) {
      const float* p = g_gp + (size_t)kh * 135168 + (size_t)(hglob * 4) * 64 + lane;
      gi += p[0]; gf += p[64]; gg += p[128]; go += p[192];
    }
    float c0 = g_c[(size_t)hglob * 64 + lane];
    float cn = sigf(gf) * c0 + sigf(gi) * tanhf(gg);
    float hn = sigf(go) * tanhf(cn);
    g_c[(size_t)hglob * 64 + lane] = cn;
    s_h[u * 64 + lane] = hn;
    __syncthreads();
    if (tid < 256) {
      int q = tid >> 6;
      float h0 = s_h[(2 * q) * 64 + lane], h1 = s_h[(2 * q + 1) * 64 + lane];
      int kp = 160 + 256 * (par ^ 1) + blk * 4 + q;
      A2[(size_t)kp * 64 + lane] = packbf(h0, h1);
    }
  } else {
    if (t == 0) return;
    int j = (blk - 64) * 8 + u;
    float v = out_b[j];
    #pragma unroll
    for (int kh = 0; kh < 4; ++kh)
      v += g_gp[(size_t)kh * 135168 + (size_t)(2048 + j) * 64 + lane];
    out[((size_t)lane * TT + (t - 1)) * DD + j] = sigf(v);
  }
}

// ============ K2: head projections GEMM, split-K x4 ============
__global__ __launch_bounds__(512) void k2_heads(
    int wslot, const uint_t* __restrict__ W2h,
    const float* __restrict__ read_b, const float* __restrict__ write_b,
    const uint_t* __restrict__ A2, float* __restrict__ g_headp) {
  const int blk = blockIdx.x, tid = threadIdx.x;
  const int lane = tid & 63, u = tid >> 6;
  const int rgrp = blk >> 2, kh = blk & 3;
  const int r = rgrp * 8 + u;
  __shared__ uint_t s_tile[64 * 64];
  __shared__ float s_tr[8 * 65];
  const int hbase = 160 + 256 * wslot + kh * 64;
  float acc = 0.f;
  const uint_t* wrow = W2h + (size_t)r * 256 + kh * 64;
  for (int i = tid; i < 64 * 64; i += 512) {
    int kk = i >> 6, bb = i & 63;
    s_tile[i] = A2[(size_t)(hbase + kk) * 64 + bb];
  }
  __syncthreads();
  #pragma unroll 4
  for (int kk = 0; kk < 64; ++kk) {
    uint_t ua = s_tile[kk * 64 + lane];
    uint_t w = wrow[kk];
    acc += bflo(w) * bflo(ua) + bfhi(w) * bfhi(ua);
  }
  __syncthreads();
  if (kh == 0) acc += (r < 280) ? read_b[r] : write_b[r - 280];
  s_tr[u * 65 + lane] = acc;
  __syncthreads();
  if (tid < 128) {
    int bb = tid & 63, half = tid >> 6;
    float4 v;
    v.x = s_tr[(half * 4 + 0) * 65 + bb];
    v.y = s_tr[(half * 4 + 1) * 65 + bb];
    v.z = s_tr[(half * 4 + 2) * 65 + bb];
    v.w = s_tr[(half * 4 + 3) * 65 + bb];
    *(float4*)(g_headp + (size_t)kh * 69632 + (size_t)bb * 1088 + rgrp * 8 + half * 4) = v;
  }
}

// ============ K3: per-batch memory phase — mem LDS-resident ============
// Dynamic LDS: 1024 rows x 32 uints, rotation-swizzled: slot(row,c) = (c+row)&31.
// Deferred normalization: wp staged (s_part / s_wp), 1/Z folded downstream.
__global__ __launch_bounds__(1024, 4) void k3_mem(
    int t, const float* __restrict__ x, const float* __restrict__ g_headp,
    ushort_t* __restrict__ g_mem, uint_t* __restrict__ A2,
    float* __restrict__ g_ws) {
  const int b = blockIdx.x, tid = threadIdx.x;
  const int lane = tid & 63, wave = tid >> 6;
  extern __shared__ uint_t s_mem[];            // 131072 B
  __shared__ alignas(16) float s_wgA[1024];    // wgR (shift window)
  __shared__ alignas(16) float s_wgB[1024];    // wgW (shift window)
  __shared__ alignas(16) float s_part[1024];   // wpR, then einsum partials
  __shared__ alignas(16) float s_wp[1024];     // wpW
  __shared__ alignas(16) float s_reads[RR * VV];
  __shared__ alignas(16) float s_or[72];
  __shared__ alignas(16) float s_ow[200];
  __shared__ alignas(16) float s_e[VV];
  __shared__ alignas(16) float s_a[VV];
  __shared__ float s_redR[16];
  __shared__ float s_redW[16];
  uint_t* m32 = (uint_t*)(g_mem + (size_t)b * (NN * VV));
  const float* hp = g_headp + (size_t)b * 1088;

  // ---- prefetch ws history into registers ----
  float wsr[8];
  #pragma unroll
  for (int s2 = 0; s2 < 8; ++s2) wsr[s2] = g_ws[(size_t)(b * 8 + s2) * 1024 + tid];

  // ---- proj load head 0 (sum 4 split-K partials) ----
  if (tid < 70) {
    float s = 0.f;
    #pragma unroll
    for (int kh = 0; kh < 4; ++kh) s += hp[(size_t)kh * 69632 + tid];
    s_or[tid] = s;
  } else if (tid >= 128 && tid < 326) {
    int i2 = tid - 128;
    float s = 0.f;
    #pragma unroll
    for (int kh = 0; kh < 4; ++kh) s += hp[(size_t)kh * 69632 + 280 + i2];
    s_ow[i2] = s;
  }
  __syncthreads();                              // P0
  if (tid < VV) { s_e[tid] = sigf(s_ow[70 + tid]); s_a[tid] = s_ow[134 + tid]; }

  for (int hd = 0; hd < RR; ++hd) {
    // ---- dot pass over own row (tid): dual keys ----
    float dotR = 0.f, dotW = 0.f, nrm2 = 0.f;
    if (hd == 0) {
      const uint4* rowp = (const uint4*)(m32 + (size_t)tid * 32);
      const float4* orf = (const float4*)s_or;
      const float4* owf = (const float4*)s_ow;
      #pragma unroll
      for (int p = 0; p < 8; ++p) {
        uint4 m = rowp[p];
        s_mem[tid * 32 + ((4 * p + 0 + tid) & 31)] = m.x;
        s_mem[tid * 32 + ((4 * p + 1 + tid) & 31)] = m.y;
        s_mem[tid * 32 + ((4 * p + 2 + tid) & 31)] = m.z;
        s_mem[tid * 32 + ((4 * p + 3 + tid) & 31)] = m.w;
        float4 ka = orf[2 * p], kb = orf[2 * p + 1];
        float4 wa = owf[2 * p], wb = owf[2 * p + 1];
        float m0 = bflo(m.x), m1 = bfhi(m.x), m2 = bflo(m.y), m3 = bfhi(m.y);
        float m4 = bflo(m.z), m5 = bfhi(m.z), m6 = bflo(m.w), m7 = bfhi(m.w);
        nrm2 += m0 * m0 + m1 * m1 + m2 * m2 + m3 * m3 + m4 * m4 + m5 * m5 + m6 * m6 + m7 * m7;
        dotR += m0 * ka.x + m1 * ka.y + m2 * ka.z + m3 * ka.w +
                m4 * kb.x + m5 * kb.y + m6 * kb.z + m7 * kb.w;
        dotW += m0 * wa.x + m1 * wa.y + m2 * wa.z + m3 * wa.w +
                m4 * wb.x + m5 * wb.y + m6 * wb.z + m7 * wb.w;
      }
    } else {
      #pragma unroll 8
      for (int c = 0; c < 32; ++c) {
        uint_t u = s_mem[tid * 32 + ((c + tid) & 31)];
        float v0 = bflo(u), v1 = bfhi(u);
        nrm2 += v0 * v0 + v1 * v1;
        dotR += v0 * s_or[2 * c] + v1 * s_or[2 * c + 1];
        dotW += v0 * s_ow[2 * c] + v1 * s_ow[2 * c + 1];
      }
    }
    // ---- per-wave key-norm reduce ----
    float kkR, kkW;
    {
      float kR = s_or[lane]; kR *= kR;
      float kW = s_ow[lane]; kW *= kW;
      #pragma unroll
      for (int o = 32; o; o >>= 1) { kR += __shfl_xor(kR, o); kW += __shfl_xor(kW, o); }
      kkR = kR; kkW = kW;
    }
    float na = fmaxf(sqrtf(nrm2), 1e-8f);

    // ---- dual softmax chain (4 syncs) ----
    float nbR = fmaxf(sqrtf(kkR), 1e-8f), nbW = fmaxf(sqrtf(kkW), 1e-8f);
    float betaR = splus(s_or[64]), betaW = splus(s_ow[64]);
    float gR = sigf(s_or[65]), gW = sigf(s_ow[65]);
    float r0 = s_or[66], r1 = s_or[67], r2 = s_or[68];
    float q0 = s_ow[66], q1 = s_ow[67], q2 = s_ow[68];
    float mxR = fmaxf(r0, fmaxf(r1, r2)), mxW = fmaxf(q0, fmaxf(q1, q2));
    float eR0 = __expf(r0 - mxR), eR1 = __expf(r1 - mxR), eR2 = __expf(r2 - mxR);
    float eW0 = __expf(q0 - mxW), eW1 = __expf(q1 - mxW), eW2 = __expf(q2 - mxW);
    float siR = 1.0f / (eR0 + eR1 + eR2), siW = 1.0f / (eW0 + eW1 + eW2);
    float gamR = 1.0f + splus(s_or[69]), gamW = 1.0f + splus(s_ow[69]);
    float eeR = __expf(betaR * dotR / (na * nbR));   // |z|<=beta: no max-sub
    float eeW = __expf(betaW * dotW / (na * nbW));
    float vR = eeR, vW = eeW;
    #pragma unroll
    for (int o = 32; o; o >>= 1) { vR += __shfl_xor(vR, o); vW += __shfl_xor(vW, o); }
    if (lane == 0) { s_redR[wave] = vR; s_redW[wave] = vW; }
    __syncthreads();                              // S1
    float SR = 0.f, SW = 0.f;
    #pragma unroll
    for (int w = 0; w < 16; ++w) { SR += s_redR[w]; SW += s_redW[w]; }
    float wgR = gR * (eeR / SR) + (1.0f - gR) * wsr[2 * hd];
    float wgW = gW * (eeW / SW) + (1.0f - gW) * wsr[2 * hd + 1];
    s_wgA[tid] = wgR;
    s_wgB[tid] = wgW;
    __syncthreads();                              // S2
    int tm = (tid + 1023) & 1023, tp = (tid + 1) & 1023;
    float wsnR = (eR0 * siR) * s_wgA[tm] + (eR1 * siR) * s_wgA[tid] + (eR2 * siR) * s_wgA[tp];
    float wsnW = (eW0 * siW) * s_wgB[tm] + (eW1 * siW) * s_wgB[tid] + (eW2 * siW) * s_wgB[tp];
    float wpR = __expf(gamR * __logf(wsnR));
    float wpW = __expf(gamW * __logf(wsnW));
    s_part[tid] = wpR;                            // unnormalized stage
    s_wp[tid] = wpW;
    vR = wpR; vW = wpW;
    #pragma unroll
    for (int o = 32; o; o >>= 1) { vR += __shfl_xor(vR, o); vW += __shfl_xor(vW, o); }
    if (lane == 0) { s_redR[wave] = vR; s_redW[wave] = vW; }
    __syncthreads();                              // S3: Z ready AND wp visible
    float ZR = 0.f, ZW = 0.f;
    #pragma unroll
    for (int w = 0; w < 16; ++w) { ZR += s_redR[w]; ZW += s_redW[w]; }
    float invZR = 1.0f / (ZR + 1e-16f);
    float invZW = 1.0f / (ZW + 1e-16f);
    float wRf = wpR * invZR;
    float wWf = wpW * invZW;
    wsr[2 * hd] = wRf;
    wsr[2 * hd + 1] = wWf;
    g_ws[(size_t)(b * 8 + 2 * hd) * 1024 + tid] = wRf;
    g_ws[(size_t)(b * 8 + 2 * hd + 1) * 1024 + tid] = wWf;

    // ---- prefetch next head's projections (hidden under einsum; s_or/ow dead) ----
    if (hd < 3) {
      if (tid < 70) {
        float s = 0.f;
        #pragma unroll
        for (int kh = 0; kh < 4; ++kh) s += hp[(size_t)kh * 69632 + (hd + 1) * 70 + tid];
        s_or[tid] = s;
      } else if (tid >= 128 && tid < 326) {
        int i2 = tid - 128;
        float s = 0.f;
        #pragma unroll
        for (int kh = 0; kh < 4; ++kh) s += hp[(size_t)kh * 69632 + 280 + (hd + 1) * 198 + i2];
        s_ow[i2] = s;
      }
    }

    // ---- fused einsum + erase in LDS (wp-scaled; head 3 erase -> EA) ----
    {
      const int cp = lane & 31, half = lane >> 5;
      const float e0 = s_e[2 * cp] * invZW, e1 = s_e[2 * cp + 1] * invZW;
      const float a0 = s_a[2 * cp] * invZW, a1 = s_a[2 * cp + 1] * invZW;
      const int rbase = wave * 64 + half;
      float acc0 = 0.f, acc1 = 0.f;
      #pragma unroll 8
      for (int q = 0; q < 32; ++q) {
        int row = rbase + 2 * q;
        int addr = row * 32 + ((cp + row) & 31);
        uint_t uu = s_mem[addr];
        float wRn = s_part[row];                  // wpR (unnormalized)
        float wWn = s_wp[row];                    // wpW (unnormalized)
        float v0 = bflo(uu), v1 = bfhi(uu);
        acc0 += wRn * v0; acc1 += wRn * v1;
        float n0 = v0 * (1.f - wWn * e0) + wWn * a0;
        float n1 = v1 * (1.f - wWn * e1) + wWn * a1;
        uint_t nu = packbf(n0, n1);
        if (hd < 3) s_mem[addr] = nu;
        else        m32[(size_t)row * 32 + cp] = nu;   // final mem -> EA, coalesced
      }
      acc0 += __shfl_xor(acc0, 32);
      acc1 += __shfl_xor(acc1, 32);
      if (half == 0) *(float2*)(s_part + wave * 64 + 2 * cp) = make_float2(acc0, acc1);
    }
    __syncthreads();                              // S5
    if (tid < VV) {
      float s = 0.f;
      #pragma unroll
      for (int w2 = 0; w2 < 16; ++w2) s += s_part[w2 * 64 + tid];
      s_reads[hd * VV + tid] = s * invZR;
      if (hd < 3) { s_e[tid] = sigf(s_ow[70 + tid]); s_a[tid] = s_ow[134 + tid]; }
    }
  } // hd
  __syncthreads();

  // publish reads_t and x_{t+1} into A (bf16 pairs)
  if (tid < 128)
    A2[(size_t)(32 + tid) * 64 + b] = packbf(s_reads[2 * tid], s_reads[2 * tid + 1]);
  if (tid < 32 && t + 1 < TT) {
    float v0 = x[((size_t)b * TT + t + 1) * DD + 2 * tid];
    float v1 = x[((size_t)b * TT + t + 1) * DD + 2 * tid + 1];
    A2[(size_t)tid * 64 + b] = packbf(v0, v1);
  }
}

extern "C" void kernel_launch(void* const* d_in, const int* in_sizes, int n_in,
                              void* d_out, int out_size, void* d_ws, size_t ws_size,
                              hipStream_t stream) {
  char* ws = (char*)d_ws;
  ushort_t* g_mem = (ushort_t*)ws;                 //  8,388,608
  uint_t* g_A2    = (uint_t*)(ws + 8388608);       //    172,032
  float* g_c      = (float*)(ws + 8560640);        //    131,072
  float* g_ws     = (float*)(ws + 8691712);        //  2,097,152
  float* g_headp  = (float*)(ws + 10788864);       //  1,114,112 (4 halves)
  uint_t* W2g     = (uint_t*)(ws + 11902976);      //  3,514,368
  uint_t* W2h     = (uint_t*)(ws + 15417344);      //  1,097,728
  float* gbias    = (float*)(ws + 16515072);       //      8,192
  float* g_gp     = (float*)(ws + 16523264);       //  2,162,688  (~18.7 MB)

  const float* x        = (const float*)d_in[0];
  const float* mem_bias = (const float*)d_in[1];
  const float* h_bias   = (const float*)d_in[2];
  const float* c_bias   = (const float*)d_in[3];
  const float* W_ih     = (const float*)d_in[4];
  const float* W_hh     = (const float*)d_in[5];
  const float* b_ih     = (const float*)d_in[6];
  const float* b_hh     = (const float*)d_in[7];
  const float* read_W   = (const float*)d_in[8];
  const float* read_b   = (const float*)d_in[9];
  const float* write_W  = (const float*)d_in[10];
  const float* write_b  = (const float*)d_in[11];
  const float* read_init= (const float*)d_in[12];
  const float* out_W    = (const float*)d_in[13];
  const float* out_b    = (const float*)d_in[14];
  float* out = (float*)d_out;

  bias_kernel<<<8, 256, 0, stream>>>(b_ih, b_hh, gbias);
  build_gw<<<3432, 256, 0, stream>>>(W_ih, W_hh, out_W, W2g);
  build_hw<<<1072, 256, 0, stream>>>(read_W, write_W, W2h);
  k0_init<<<64, 1024, 0, stream>>>(x, mem_bias, h_bias, c_bias, read_init,
                                   g_mem, g_A2, g_c, g_ws);
  for (int t = 0; t < TT; ++t) {
    k1s<<<288, 512, 0, stream>>>(t & 1, 1, (t > 0) ? 1 : 0, W2g, g_A2, g_gp);
    k1c<<<72, 512, 0, stream>>>(t, t & 1, 1, g_gp, gbias, g_A2, g_c, out_b, out);
    k2_heads<<<536, 512, 0, stream>>>((t + 1) & 1, W2h, read_b, write_b, g_A2, g_headp);
    k3_mem<<<64, 1024, 131072, stream>>>(t, x, g_headp, g_mem, g_A2, g_ws);
  }
  // final out(t=31): out partials from h_31 (slot 0) + reads_31, then combine
  k1s<<<288, 512, 0, stream>>>(0, 0, 1, W2g, g_A2, g_gp);
  k1c<<<72, 512, 0, stream>>>(TT, 0, 0, g_gp, gbias, g_A2, g_c, out_b, out);
}